// Round 5
// baseline (195.882 us; speedup 1.0000x reference)
//
#include <hip/hip_runtime.h>
#include <hip/hip_bf16.h>
#include <cstdint>

typedef __bf16 bf16x8 __attribute__((ext_vector_type(8)));
typedef __bf16 bf16x4 __attribute__((ext_vector_type(4)));
typedef float  f32x4  __attribute__((ext_vector_type(4)));

__device__ __forceinline__ int div25(int v) { return (v * 1311) >> 15; }  // exact for v <= 1310

#if __has_builtin(__builtin_amdgcn_exp2f)
__device__ __forceinline__ float fast_exp2(float x) { return __builtin_amdgcn_exp2f(x); }
#else
__device__ __forceinline__ float fast_exp2(float x) { return exp2f(x); }
#endif

// async global->LDS, 16B per lane; dest must be wave-uniform base + lane*16 (linear)
__device__ __forceinline__ void gll16(const __bf16* g, __bf16* l)
{
    __builtin_amdgcn_global_load_lds(
        (__attribute__((address_space(1))) void*)(g),
        (__attribute__((address_space(3))) void*)(l),
        16, 0, 0);
}

// ---- inline dtype sniff: 16 uniform halfwords from one cache line ----
__device__ __forceinline__ int sniff_isbf(const void* p)
{
    const unsigned short* x = (const unsigned short*)p;
    int cnt = 0;
    #pragma unroll
    for (int i = 0; i < 16; ++i) {
        int e = (x[2 * i] >> 7) & 0xFF;
        cnt += (e >= 90 && e <= 143) ? 1 : 0;
    }
    return cnt > 8;
}

// ================= fused preprocessing: one launch, 3 independent jobs =================
// blocks [0,1280): x transpose+cvt  (b,256,625)->xT (b,640,256), pad rows zeroed
// blocks [1280,1344): weight prep   Wqkv/Wout -> Wt/WoT (transposed, qscale*log2e folded)
// blocks [1344,1664): bias table, packed: biasC[((h*40+ig)*20+jc)*512 + lane*8 + js*4 + rr]
__global__ __launch_bounds__(256) void k_pre(
    const void* __restrict__ x, const void* __restrict__ Wqkv,
    const void* __restrict__ Wout, const void* __restrict__ rel,
    __bf16* __restrict__ xT, __bf16* __restrict__ Wt, __bf16* __restrict__ WoT,
    __bf16* __restrict__ biasC)
{
    __shared__ float tile[64][65];
    int bid = blockIdx.x;
    if (bid < 1280) {
        // ---- x transpose ----
        int isbf = sniff_isbf(x);
        int b = bid / 40, rem = bid % 40;
        int c0 = (rem % 10) * 64, r0 = (rem / 10) * 64;
        const int R = 256, C = 625, Cpad = 640;
        int tc = threadIdx.x & 63, tg = threadIdx.x >> 6;
        const unsigned short* sb = (const unsigned short*)x + (size_t)b * (256 * 625);
        const float*          sf = (const float*)x          + (size_t)b * (256 * 625);
        #pragma unroll
        for (int rr = 0; rr < 16; ++rr) {
            int r = r0 + tg * 16 + rr, c = c0 + tc;
            float v = 0.f;
            if (r < R && c < C) {
                if (isbf) v = __uint_as_float((unsigned int)sb[r * C + c] << 16);
                else      v = sf[r * C + c];
            }
            tile[tg * 16 + rr][tc] = v;
        }
        __syncthreads();
        __bf16* d = xT + (size_t)b * (640 * 256);
        #pragma unroll
        for (int rr = 0; rr < 16; ++rr) {
            int c = c0 + tg * 16 + rr, r = r0 + tc;
            if (c < Cpad && r < R) d[(size_t)c * R + r] = (__bf16)tile[tc][tg * 16 + rr];
        }
    } else if (bid < 1344) {
        // ---- weight prep ----
        int q = bid - 1280;
        int bx = q % 16, by = q / 16;
        int isbf = sniff_isbf(Wqkv);
        int isqkv = (bx < 12);
        int bxx = isqkv ? bx : (bx - 12);
        const void* src = isqkv ? Wqkv : Wout;
        __bf16* dst = isqkv ? Wt : WoT;
        int R = 256, C = isqkv ? 768 : 256;
        int r0 = by * 64, c0 = bxx * 64;
        int tc = threadIdx.x & 63, tg = threadIdx.x >> 6;
        const unsigned short* sb = (const unsigned short*)src;
        const float*          sf = (const float*)src;
        #pragma unroll
        for (int rr = 0; rr < 16; ++rr) {
            int r = r0 + tg * 16 + rr, c = c0 + tc;
            float v;
            if (isbf) v = __uint_as_float((unsigned int)sb[r * C + c] << 16);
            else      v = sf[r * C + c];
            tile[tg * 16 + rr][tc] = v;
        }
        __syncthreads();
        const float qs = 0.25503494f;  // 32^-0.5 * log2(e)
        #pragma unroll
        for (int rr = 0; rr < 16; ++rr) {
            int c = c0 + tg * 16 + rr, r = r0 + tc;
            float v = tile[tc][tg * 16 + rr];
            if (isqkv && c < 256) v *= qs;
            dst[(size_t)c * R + r] = (__bf16)v;
        }
    } else {
        // ---- bias table (packed per-lane layout) ----
        const float LOG2E = 1.4426950408889634f;
        int isbf = sniff_isbf(rel);
        int q = bid - 1344;
        int ig = q % 40, h = q / 40;
        for (int t0 = 0; t0 < 10; ++t0) {
            int t  = t0 * 256 + threadIdx.x;
            int jc = t >> 7;
            int js = (t >> 6) & 1;
            int ln = t & 63;
            int qd = ln >> 4, l = ln & 15;
            int i = ig * 16 + l;
            int di = div25(i), ri = i - 25 * di;
            bf16x4 out;
            #pragma unroll
            for (int rr = 0; rr < 4; ++rr) {
                int j = jc * 32 + js * 16 + qd * 4 + rr;
                float v;
                if (j >= 625) {
                    v = -43281.f;
                } else {
                    int dj = div25(j);
                    int idx = (di - dj + 24) * 49 + ri - (j - 25 * dj) + 24;
                    idx = min(max(idx, 0), 2400);
                    float r;
                    if (isbf) r = (float)((const __bf16*)rel)[idx * 8 + h];
                    else      r = ((const float*)rel)[idx * 8 + h];
                    v = r * LOG2E;
                }
                out[rr] = (__bf16)v;
            }
            *(bf16x4*)(biasC + ((size_t)(h * 40 + ig) * 20 + jc) * 512 + ln * 8 + js * 4) = out;
        }
    }
}

// -------- QKV projection, 128x128 tile, BK=32, global_load_lds staging (m97 pattern) ----
// LDS linear [128][32] per operand (fragment b128 reads are 2-way bank-aliased = free).
#define AS(r, c) pool[(size_t)(r) * 32 + (c)]
#define BS(r, c) pool[4096 + (size_t)(r) * 32 + (c)]
#define CS(r, c) pool[(size_t)(r) * 44 + (c)]
__global__ __launch_bounds__(256, 2) void k_qkv(
    const __bf16* __restrict__ xT,   // (b,640,256), pad rows zeroed
    const __bf16* __restrict__ Wt,   // (768,256)
    __bf16* __restrict__ Q,          // (b,8,640,32) scaled by 32^-.5*log2e
    __bf16* __restrict__ Km,         // (b,8,640,32)
    __bf16* __restrict__ Vt)         // (b,8,32,640)
{
    __shared__ __align__(16) __bf16 pool[8192];
    // XCD swizzle: L%8 = XCD (round-robin). 960 = 8 XCD * 20 pairs * 6 jt.
    int L = blockIdx.x;
    int xcd = L & 7;
    int cc  = L >> 3;                 // 0..119 within XCD
    int pairIdx = xcd * 20 + cc / 6;  // 0..159 = (b,pt) pair
    int jt = cc - (cc / 6) * 6;
    int b  = pairIdx / 5;
    int pt = pairIdx - b * 5;
    int p0 = pt * 128, j0 = jt * 128;
    int tid = threadIdx.x;
    int w = tid >> 6, lane = tid & 63;
    int quad = lane >> 4, l15 = lane & 15;
    int wr = w >> 1, wc = w & 1;

    int srow = tid >> 2, scg = (tid & 3) * 8;
    const __bf16* ag  = xT + ((size_t)(b * 640 + p0 + srow) * 256) + scg;
    const __bf16* ag2 = ag + 64 * 256;
    const __bf16* bg  = Wt + ((size_t)(j0 + srow) * 256) + scg;
    const __bf16* bg2 = bg + 64 * 256;

    f32x4 acc[4][4] = {};
    for (int kk = 0; kk < 8; ++kk) {
        int c0 = kk * 32;
        __syncthreads();                       // prev iter's ds_reads done before overwrite
        gll16(ag  + c0, &AS(srow, scg));       // A rows 0-63   (dest = tid*16 B, linear)
        gll16(ag2 + c0, &AS(64 + srow, scg));  // A rows 64-127
        gll16(bg  + c0, &BS(srow, scg));
        gll16(bg2 + c0, &BS(64 + srow, scg));
        __syncthreads();                       // drains vmcnt (loads landed in LDS)
        bf16x8 af[4], bfr[4];
        #pragma unroll
        for (int t = 0; t < 4; ++t) {
            af[t]  = *(const bf16x8*)(&AS(wr * 64 + t * 16 + l15, quad * 8));
            bfr[t] = *(const bf16x8*)(&BS(wc * 64 + t * 16 + l15, quad * 8));
        }
        #pragma unroll
        for (int i = 0; i < 4; ++i)
            #pragma unroll
            for (int j = 0; j < 4; ++j)
                acc[i][j] = __builtin_amdgcn_mfma_f32_16x16x32_bf16(af[i], bfr[j], acc[i][j], 0, 0, 0);
    }

    if (jt < 4) {
        for (int r = 0; r < 4; ++r) {
            __syncthreads();
            if (wc == (r >> 1)) {
                #pragma unroll
                for (int i = 0; i < 4; ++i) {
                    #pragma unroll
                    for (int js = 0; js < 2; ++js) {
                        int jp = (r & 1) * 2 + js;
                        int col = js * 16 + l15;
                        int prow = wr * 64 + i * 16 + quad * 4;
                        #pragma unroll
                        for (int rr = 0; rr < 4; ++rr)
                            CS(prow + rr, col) = (__bf16)acc[i][jp][rr];
                    }
                }
            }
            __syncthreads();
            int jj = j0 + r * 32;
            __bf16* dst; int hh;
            if (jj < 256) { hh = jj >> 5; dst = Q; }
            else          { hh = (jj - 256) >> 5; dst = Km; }
            int p = tid >> 1, d0 = (tid & 1) * 16;
            size_t base = ((size_t)((b * 8 + hh) * 640) + p0 + p) * 32 + d0;
            #pragma unroll
            for (int k4 = 0; k4 < 4; ++k4) {
                bf16x4 v4 = *(const bf16x4*)(&CS(p, d0 + k4 * 4));
                *(bf16x4*)(dst + base + k4 * 4) = v4;
            }
        }
    } else {
        #pragma unroll
        for (int i = 0; i < 4; ++i) {
            #pragma unroll
            for (int j = 0; j < 4; ++j) {
                int jj = j0 + wc * 64 + j * 16 + l15 - 512;
                int h = jj >> 5, t = jj & 31;
                int p = p0 + wr * 64 + i * 16 + quad * 4;
                bf16x4 vv;
                #pragma unroll
                for (int rr = 0; rr < 4; ++rr) vv[rr] = (__bf16)acc[i][j][rr];
                *(bf16x4*)(Vt + ((size_t)((b * 8 + h) * 32) + t) * 640 + p) = vv;
            }
        }
    }
}

// -------- fused attention v12: 32-row wave tiles (grid 256x10, 20 waves/CU) -----------
// R2's 2x-occupancy retry, with the failure mechanism removed:
//  - ctx is now HEAD-MAJOR (b,8,640,32): no 128B line spans two heads' (=two XCDs')
//    segments -> kills the 10x write amplification R2 measured (WRITE 110MB -> ~10MB).
//  - ctx stores + Q loads nontemporal (touched once) to keep K/V/bias L2-resident.
//  - P stride 44 (verified conflict-free), packed bias bf16x8 loads (verified r4).
__global__ __launch_bounds__(128, 5) void k_attn(
    const __bf16* __restrict__ Q,
    const __bf16* __restrict__ Km,
    const __bf16* __restrict__ Vt,
    const __bf16* __restrict__ biasC,  // packed C-fragment order, *log2e
    __bf16* __restrict__ ctxH)         // (b,8,640,32) head-major
{
    __shared__ __align__(16) __bf16 P[2][2][32][44];   // [wave][buf][i][j] 11.3 KB
    __shared__ float ssum[2][32];
    int bh = blockIdx.x, b = bh >> 3, h = bh & 7;
    int tid = threadIdx.x, w = tid >> 6, lane = tid & 63;
    int quad = lane >> 4, l15 = lane & 15;
    int i0 = (blockIdx.y * 2 + w) * 32;

    bf16x8 qa[2];
    #pragma unroll
    for (int m = 0; m < 2; ++m)
        qa[m] = __builtin_nontemporal_load(
            (const bf16x8*)(Q + ((size_t)bh * 640 + i0 + 16 * m + l15) * 32 + quad * 8));
    const __bf16* kbase = Km + (size_t)bh * 640 * 32 + quad * 8;
    const __bf16* vbase = Vt + ((size_t)bh * 32 + l15) * 640 + quad * 8;
    const __bf16* bcb   = biasC + (size_t)(h * 40 + (i0 >> 4)) * 10240 + lane * 8;

    f32x4 o[2][2] = {};
    float psum[2] = {0.f, 0.f};

    // preload chunk 0 K + bias
    bf16x8 k0 = *(const bf16x8*)(kbase + (size_t)l15 * 32);
    bf16x8 k1 = *(const bf16x8*)(kbase + (size_t)(16 + l15) * 32);
    bf16x8 bc[2];
    #pragma unroll
    for (int m = 0; m < 2; ++m)
        bc[m] = *(const bf16x8*)(bcb + m * 10240);
    bf16x8 vC0 = {}, vC1 = {};

    for (int c = 0; c < 20; ++c) {
        int buf = c & 1;
        // ---- S-MFMAs for chunk c (K/bias already resident) ----
        f32x4 s[2][2];
        __builtin_amdgcn_s_setprio(1);
        #pragma unroll
        for (int m = 0; m < 2; ++m) {
            f32x4 f0, f1;
            #pragma unroll
            for (int rr = 0; rr < 4; ++rr) { f0[rr] = (float)bc[m][rr]; f1[rr] = (float)bc[m][4 + rr]; }
            s[m][0] = __builtin_amdgcn_mfma_f32_16x16x32_bf16(k0, qa[m], f0, 0, 0, 0);
            s[m][1] = __builtin_amdgcn_mfma_f32_16x16x32_bf16(k1, qa[m], f1, 0, 0, 0);
        }
        __builtin_amdgcn_s_setprio(0);
        // ---- issue prefetches: K/bias for c+1, V for c ----
        int cn = min(c + 1, 19);
        bf16x8 k0n = *(const bf16x8*)(kbase + (size_t)(cn * 32 + l15) * 32);
        bf16x8 k1n = *(const bf16x8*)(kbase + (size_t)(cn * 32 + 16 + l15) * 32);
        bf16x8 vN0 = *(const bf16x8*)(vbase + c * 32);
        bf16x8 vN1 = *(const bf16x8*)(vbase + (size_t)16 * 640 + c * 32);
        bf16x8 bn[2];
        #pragma unroll
        for (int m = 0; m < 2; ++m)
            bn[m] = *(const bf16x8*)(bcb + m * 10240 + cn * 512);
        // ---- exp/pack for chunk c (held in regs) ----
        bf16x4 pk[2][2];
        #pragma unroll
        for (int m = 0; m < 2; ++m) {
            #pragma unroll
            for (int rr = 0; rr < 4; ++rr) {
                float e0 = fast_exp2(s[m][0][rr]); psum[m] += e0; pk[m][0][rr] = (__bf16)e0;
                float e1 = fast_exp2(s[m][1][rr]); psum[m] += e1; pk[m][1][rr] = (__bf16)e1;
            }
        }
        // ---- PV for chunk c-1 (P written one full iteration ago) ----
        if (c > 0) {
            __builtin_amdgcn_s_setprio(1);
            #pragma unroll
            for (int m = 0; m < 2; ++m) {
                bf16x8 pa = *(const bf16x8*)(&P[w][buf ^ 1][16 * m + l15][quad * 8]);
                o[m][0] = __builtin_amdgcn_mfma_f32_16x16x32_bf16(pa, vC0, o[m][0], 0, 0, 0);
                o[m][1] = __builtin_amdgcn_mfma_f32_16x16x32_bf16(pa, vC1, o[m][1], 0, 0, 0);
            }
            __builtin_amdgcn_s_setprio(0);
        }
        // ---- write P(c) (read next iteration) ----
        #pragma unroll
        for (int m = 0; m < 2; ++m) {
            *(bf16x4*)(&P[w][buf][16 * m + l15][quad * 4])      = pk[m][0];
            *(bf16x4*)(&P[w][buf][16 * m + l15][16 + quad * 4]) = pk[m][1];
        }
        k0 = k0n; k1 = k1n; vC0 = vN0; vC1 = vN1;
        #pragma unroll
        for (int m = 0; m < 2; ++m) bc[m] = bn[m];
    }
    // final PV (chunk 19, buf 1)
    __builtin_amdgcn_s_setprio(1);
    #pragma unroll
    for (int m = 0; m < 2; ++m) {
        bf16x8 pa = *(const bf16x8*)(&P[w][1][16 * m + l15][quad * 8]);
        o[m][0] = __builtin_amdgcn_mfma_f32_16x16x32_bf16(pa, vC0, o[m][0], 0, 0, 0);
        o[m][1] = __builtin_amdgcn_mfma_f32_16x16x32_bf16(pa, vC1, o[m][1], 0, 0, 0);
    }
    __builtin_amdgcn_s_setprio(0);

    // row sums: i lane-resident; reduce over quads
    #pragma unroll
    for (int m = 0; m < 2; ++m) {
        psum[m] += __shfl_xor(psum[m], 16);
        psum[m] += __shfl_xor(psum[m], 32);
    }
    if (quad == 0)
        #pragma unroll
        for (int m = 0; m < 2; ++m) ssum[w][16 * m + l15] = psum[m];
    #pragma unroll
    for (int m = 0; m < 2; ++m) {
        #pragma unroll
        for (int rr = 0; rr < 4; ++rr) {
            int il = 16 * m + quad * 4 + rr;
            float inv = 1.f / ssum[w][il];
            size_t base = ((size_t)(b * 8 + h) * 640 + i0 + il) * 32;
            __builtin_nontemporal_store((__bf16)(o[m][0][rr] * inv), &ctxH[base + l15]);
            __builtin_nontemporal_store((__bf16)(o[m][1][rr] * inv), &ctxH[base + 16 + l15]);
        }
    }
}

// -------- output projection, 64x256 tile, BK=32; reads head-major ctx ----------------
__global__ __launch_bounds__(256, 2) void k_outproj(
    const __bf16* __restrict__ ctxH,  // (b,8,640,32) head-major
    const __bf16* __restrict__ WoT,   // (256,256)
    const void* __restrict__ xorig,   // dtype sniff only
    void* __restrict__ out)           // (b,256,625)
{
    __shared__ __align__(16) __bf16 As2[64][40];
    __shared__ __align__(16) __bf16 Bs2[256][40];
    int isbf = sniff_isbf(xorig);
    int b = blockIdx.y, pt = blockIdx.x;
    int p0 = pt * 64;
    int tid = threadIdx.x, w = tid >> 6, lane = tid & 63;
    int quad = lane >> 4, l15 = lane & 15;
    int srow = tid >> 2, scg = (tid & 3) * 8;
    const __bf16* bg = WoT + (size_t)srow * 256 + scg;

    f32x4 acc[4][4] = {};
    for (int kk = 0; kk < 8; ++kk) {
        int c0 = kk * 32;
        // A-panel for k-block kk = head kk's 32 channels, rows p0+srow (coalesced 16B/lane)
        bf16x8 a0 = *(const bf16x8*)(ctxH + (((size_t)(b * 8 + kk) * 640) + p0 + srow) * 32 + scg);
        bf16x8 b0 = *(const bf16x8*)(bg + c0);
        bf16x8 b1 = *(const bf16x8*)(bg + 64 * 256 + c0);
        bf16x8 b2 = *(const bf16x8*)(bg + 128 * 256 + c0);
        bf16x8 b3 = *(const bf16x8*)(bg + 192 * 256 + c0);
        __syncthreads();
        *(bf16x8*)(&As2[srow][scg])       = a0;
        *(bf16x8*)(&Bs2[srow][scg])       = b0;
        *(bf16x8*)(&Bs2[64 + srow][scg])  = b1;
        *(bf16x8*)(&Bs2[128 + srow][scg]) = b2;
        *(bf16x8*)(&Bs2[192 + srow][scg]) = b3;
        __syncthreads();
        bf16x8 af[4], bfr[4];
        #pragma unroll
        for (int t = 0; t < 4; ++t) {
            af[t]  = *(const bf16x8*)(&As2[t * 16 + l15][quad * 8]);
            bfr[t] = *(const bf16x8*)(&Bs2[w * 64 + t * 16 + l15][quad * 8]);
        }
        #pragma unroll
        for (int i = 0; i < 4; ++i)
            #pragma unroll
            for (int j = 0; j < 4; ++j)
                acc[i][j] = __builtin_amdgcn_mfma_f32_16x16x32_bf16(af[i], bfr[j], acc[i][j], 0, 0, 0);
    }
    __bf16* outb = (__bf16*)out;
    float*  outf = (float*)out;
    #pragma unroll
    for (int i = 0; i < 4; ++i) {
        #pragma unroll
        for (int j = 0; j < 4; ++j) {
            int co = w * 64 + j * 16 + l15;
            #pragma unroll
            for (int rr = 0; rr < 4; ++rr) {
                int p = p0 + i * 16 + quad * 4 + rr;
                if (p < 625) {
                    size_t o = ((size_t)(b * 256) + co) * 625 + p;
                    if (isbf) outb[o] = (__bf16)acc[i][j][rr];
                    else      outf[o] = acc[i][j][rr];
                }
            }
        }
    }
}

extern "C" void kernel_launch(void* const* d_in, const int* in_sizes, int n_in,
                              void* d_out, int out_size, void* d_ws, size_t ws_size,
                              hipStream_t stream)
{
    const void* x    = d_in[0];
    const void* Wqkv = d_in[1];
    const void* Wout = d_in[2];
    const void* rel  = d_in[3];

    // ws layout, NO aliasing (ws_size is 256 MiB per the harness fill; we use ~70 MB).
    __bf16* ws    = (__bf16*)d_ws;
    __bf16* xT    = ws;                      // 10,485,760 elems
    __bf16* Wt    = xT + 10485760;           //    196,608
    __bf16* WoT   = Wt + 196608;             //     65,536
    __bf16* Q     = WoT + 65536;             //  5,242,880
    __bf16* Km    = Q + 5242880;             //  5,242,880
    __bf16* Vt    = Km + 5242880;            //  5,242,880
    __bf16* biasC = Vt + 5242880;            //  3,276,800
    __bf16* ctxH  = biasC + 3276800;         //  5,242,880   (total ~70 MB)

    k_pre<<<1664, 256, 0, stream>>>(x, Wqkv, Wout, rel, xT, Wt, WoT, biasC);
    k_qkv<<<dim3(960), 256, 0, stream>>>(xT, Wt, Q, Km, Vt);
    k_attn<<<dim3(256, 10), 128, 0, stream>>>(Q, Km, Vt, biasC, ctxH);
    k_outproj<<<dim3(10, 32), 256, 0, stream>>>(ctxH, WoT, x, d_out);
}

// Round 6
// 166.009 us; speedup vs baseline: 1.1800x; 1.1800x over previous
//
#include <hip/hip_runtime.h>
#include <hip/hip_bf16.h>
#include <cstdint>

typedef __bf16 bf16x8 __attribute__((ext_vector_type(8)));
typedef __bf16 bf16x4 __attribute__((ext_vector_type(4)));
typedef float  f32x4  __attribute__((ext_vector_type(4)));

__device__ __forceinline__ int div25(int v) { return (v * 1311) >> 15; }  // exact for v <= 1310

#if __has_builtin(__builtin_amdgcn_exp2f)
__device__ __forceinline__ float fast_exp2(float x) { return __builtin_amdgcn_exp2f(x); }
#else
__device__ __forceinline__ float fast_exp2(float x) { return exp2f(x); }
#endif

// async global->LDS, 16B per lane; dest must be wave-uniform base + lane*16 (linear)
__device__ __forceinline__ void gll16(const __bf16* g, __bf16* l)
{
    __builtin_amdgcn_global_load_lds(
        (__attribute__((address_space(1))) void*)(g),
        (__attribute__((address_space(3))) void*)(l),
        16, 0, 0);
}

// ---- inline dtype sniff: 16 uniform halfwords from one cache line ----
__device__ __forceinline__ int sniff_isbf(const void* p)
{
    const unsigned short* x = (const unsigned short*)p;
    int cnt = 0;
    #pragma unroll
    for (int i = 0; i < 16; ++i) {
        int e = (x[2 * i] >> 7) & 0xFF;
        cnt += (e >= 90 && e <= 143) ? 1 : 0;
    }
    return cnt > 8;
}

// ================= fused preprocessing: one launch, 3 independent jobs =================
// blocks [0,1280): x transpose+cvt  (b,256,625)->xT (b,640,256), pad rows zeroed
// blocks [1280,1344): weight prep   Wqkv/Wout -> Wt/WoT (transposed, qscale*log2e folded)
// blocks [1344,1664): bias table in MFMA C-fragment order, *log2e, stored F32
//   layout: biasF[((h*40+ig)*20+jc)*512 + lane*8 + js*4 + rr]  (f32 elements)
//   -> k_attn uses it directly as the MFMA C operand, no per-chunk cvt.
__global__ __launch_bounds__(256) void k_pre(
    const void* __restrict__ x, const void* __restrict__ Wqkv,
    const void* __restrict__ Wout, const void* __restrict__ rel,
    __bf16* __restrict__ xT, __bf16* __restrict__ Wt, __bf16* __restrict__ WoT,
    float* __restrict__ biasF)
{
    __shared__ float tile[64][65];
    int bid = blockIdx.x;
    if (bid < 1280) {
        // ---- x transpose ----
        int isbf = sniff_isbf(x);
        int b = bid / 40, rem = bid % 40;
        int c0 = (rem % 10) * 64, r0 = (rem / 10) * 64;
        const int R = 256, C = 625, Cpad = 640;
        int tc = threadIdx.x & 63, tg = threadIdx.x >> 6;
        const unsigned short* sb = (const unsigned short*)x + (size_t)b * (256 * 625);
        const float*          sf = (const float*)x          + (size_t)b * (256 * 625);
        #pragma unroll
        for (int rr = 0; rr < 16; ++rr) {
            int r = r0 + tg * 16 + rr, c = c0 + tc;
            float v = 0.f;
            if (r < R && c < C) {
                if (isbf) v = __uint_as_float((unsigned int)sb[r * C + c] << 16);
                else      v = sf[r * C + c];
            }
            tile[tg * 16 + rr][tc] = v;
        }
        __syncthreads();
        __bf16* d = xT + (size_t)b * (640 * 256);
        #pragma unroll
        for (int rr = 0; rr < 16; ++rr) {
            int c = c0 + tg * 16 + rr, r = r0 + tc;
            if (c < Cpad && r < R) d[(size_t)c * R + r] = (__bf16)tile[tc][tg * 16 + rr];
        }
    } else if (bid < 1344) {
        // ---- weight prep ----
        int q = bid - 1280;
        int bx = q % 16, by = q / 16;
        int isbf = sniff_isbf(Wqkv);
        int isqkv = (bx < 12);
        int bxx = isqkv ? bx : (bx - 12);
        const void* src = isqkv ? Wqkv : Wout;
        __bf16* dst = isqkv ? Wt : WoT;
        int R = 256, C = isqkv ? 768 : 256;
        int r0 = by * 64, c0 = bxx * 64;
        int tc = threadIdx.x & 63, tg = threadIdx.x >> 6;
        const unsigned short* sb = (const unsigned short*)src;
        const float*          sf = (const float*)src;
        #pragma unroll
        for (int rr = 0; rr < 16; ++rr) {
            int r = r0 + tg * 16 + rr, c = c0 + tc;
            float v;
            if (isbf) v = __uint_as_float((unsigned int)sb[r * C + c] << 16);
            else      v = sf[r * C + c];
            tile[tg * 16 + rr][tc] = v;
        }
        __syncthreads();
        const float qs = 0.25503494f;  // 32^-0.5 * log2(e)
        #pragma unroll
        for (int rr = 0; rr < 16; ++rr) {
            int c = c0 + tg * 16 + rr, r = r0 + tc;
            float v = tile[tc][tg * 16 + rr];
            if (isqkv && c < 256) v *= qs;
            dst[(size_t)c * R + r] = (__bf16)v;
        }
    } else {
        // ---- bias table (packed per-lane layout, f32) ----
        const float LOG2E = 1.4426950408889634f;
        int isbf = sniff_isbf(rel);
        int q = bid - 1344;
        int ig = q % 40, h = q / 40;
        for (int t0 = 0; t0 < 10; ++t0) {
            int t  = t0 * 256 + threadIdx.x;
            int jc = t >> 7;
            int js = (t >> 6) & 1;
            int ln = t & 63;
            int qd = ln >> 4, l = ln & 15;
            int i = ig * 16 + l;
            int di = div25(i), ri = i - 25 * di;
            f32x4 fout;
            #pragma unroll
            for (int rr = 0; rr < 4; ++rr) {
                int j = jc * 32 + js * 16 + qd * 4 + rr;
                float v;
                if (j >= 625) {
                    v = -43281.f;
                } else {
                    int dj = div25(j);
                    int idx = (di - dj + 24) * 49 + ri - (j - 25 * dj) + 24;
                    idx = min(max(idx, 0), 2400);
                    float r;
                    if (isbf) r = (float)((const __bf16*)rel)[idx * 8 + h];
                    else      r = ((const float*)rel)[idx * 8 + h];
                    v = r * LOG2E;
                }
                fout[rr] = v;
            }
            *(f32x4*)(biasF + ((size_t)(h * 40 + ig) * 20 + jc) * 512 + ln * 8 + js * 4) = fout;
        }
    }
}

// -------- QKV projection, 128x128 tile, BK=32, global_load_lds staging (m97 pattern) ----
// LDS linear [128][32] per operand (fragment b128 reads are 2-way bank-aliased = free).
#define AS(r, c) pool[(size_t)(r) * 32 + (c)]
#define BS(r, c) pool[4096 + (size_t)(r) * 32 + (c)]
#define CS(r, c) pool[(size_t)(r) * 44 + (c)]
__global__ __launch_bounds__(256, 2) void k_qkv(
    const __bf16* __restrict__ xT,   // (b,640,256), pad rows zeroed
    const __bf16* __restrict__ Wt,   // (768,256)
    __bf16* __restrict__ Q,          // (b,8,640,32) scaled by 32^-.5*log2e
    __bf16* __restrict__ Km,         // (b,8,640,32)
    __bf16* __restrict__ Vt)         // (b,8,32,640)
{
    __shared__ __align__(16) __bf16 pool[8192];
    // XCD swizzle: L%8 = XCD (round-robin). 960 = 8 XCD * 20 pairs * 6 jt.
    int L = blockIdx.x;
    int xcd = L & 7;
    int cc  = L >> 3;                 // 0..119 within XCD
    int pairIdx = xcd * 20 + cc / 6;  // 0..159 = (b,pt) pair
    int jt = cc - (cc / 6) * 6;
    int b  = pairIdx / 5;
    int pt = pairIdx - b * 5;
    int p0 = pt * 128, j0 = jt * 128;
    int tid = threadIdx.x;
    int w = tid >> 6, lane = tid & 63;
    int quad = lane >> 4, l15 = lane & 15;
    int wr = w >> 1, wc = w & 1;

    int srow = tid >> 2, scg = (tid & 3) * 8;
    const __bf16* ag  = xT + ((size_t)(b * 640 + p0 + srow) * 256) + scg;
    const __bf16* ag2 = ag + 64 * 256;
    const __bf16* bg  = Wt + ((size_t)(j0 + srow) * 256) + scg;
    const __bf16* bg2 = bg + 64 * 256;

    f32x4 acc[4][4] = {};
    for (int kk = 0; kk < 8; ++kk) {
        int c0 = kk * 32;
        __syncthreads();                       // prev iter's ds_reads done before overwrite
        gll16(ag  + c0, &AS(srow, scg));       // A rows 0-63   (dest = tid*16 B, linear)
        gll16(ag2 + c0, &AS(64 + srow, scg));  // A rows 64-127
        gll16(bg  + c0, &BS(srow, scg));
        gll16(bg2 + c0, &BS(64 + srow, scg));
        __syncthreads();                       // drains vmcnt (loads landed in LDS)
        bf16x8 af[4], bfr[4];
        #pragma unroll
        for (int t = 0; t < 4; ++t) {
            af[t]  = *(const bf16x8*)(&AS(wr * 64 + t * 16 + l15, quad * 8));
            bfr[t] = *(const bf16x8*)(&BS(wc * 64 + t * 16 + l15, quad * 8));
        }
        #pragma unroll
        for (int i = 0; i < 4; ++i)
            #pragma unroll
            for (int j = 0; j < 4; ++j)
                acc[i][j] = __builtin_amdgcn_mfma_f32_16x16x32_bf16(af[i], bfr[j], acc[i][j], 0, 0, 0);
    }

    if (jt < 4) {
        for (int r = 0; r < 4; ++r) {
            __syncthreads();
            if (wc == (r >> 1)) {
                #pragma unroll
                for (int i = 0; i < 4; ++i) {
                    #pragma unroll
                    for (int js = 0; js < 2; ++js) {
                        int jp = (r & 1) * 2 + js;
                        int col = js * 16 + l15;
                        int prow = wr * 64 + i * 16 + quad * 4;
                        #pragma unroll
                        for (int rr = 0; rr < 4; ++rr)
                            CS(prow + rr, col) = (__bf16)acc[i][jp][rr];
                    }
                }
            }
            __syncthreads();
            int jj = j0 + r * 32;
            __bf16* dst; int hh;
            if (jj < 256) { hh = jj >> 5; dst = Q; }
            else          { hh = (jj - 256) >> 5; dst = Km; }
            int p = tid >> 1, d0 = (tid & 1) * 16;
            size_t base = ((size_t)((b * 8 + hh) * 640) + p0 + p) * 32 + d0;
            #pragma unroll
            for (int k4 = 0; k4 < 4; ++k4) {
                bf16x4 v4 = *(const bf16x4*)(&CS(p, d0 + k4 * 4));
                *(bf16x4*)(dst + base + k4 * 4) = v4;
            }
        }
    } else {
        #pragma unroll
        for (int i = 0; i < 4; ++i) {
            #pragma unroll
            for (int j = 0; j < 4; ++j) {
                int jj = j0 + wc * 64 + j * 16 + l15 - 512;
                int h = jj >> 5, t = jj & 31;
                int p = p0 + wr * 64 + i * 16 + quad * 4;
                bf16x4 vv;
                #pragma unroll
                for (int rr = 0; rr < 4; ++rr) vv[rr] = (__bf16)acc[i][j][rr];
                *(bf16x4*)(Vt + ((size_t)((b * 8 + h) * 32) + t) * 640 + p) = vv;
            }
        }
    }
}

// -------- fused attention v13: v11 structure (best, R4) + f32 bias as direct C operand --
// R4 base (64-row waves, grid 256x5, P stride 44, depth-1 prefetch) is the verified
// optimum of the L2-vs-occupancy trade (R2/R3/R5 all lost moving off it).
// Change here: biasF is f32 in C-fragment order -> MFMA C input directly, deleting
// 32 bf16->f32 converts per chunk (~25% of the wave's VALU work).
__global__ __launch_bounds__(128, 3) void k_attn(
    const __bf16* __restrict__ Q,
    const __bf16* __restrict__ Km,
    const __bf16* __restrict__ Vt,
    const float* __restrict__ biasF,   // packed C-fragment order, *log2e, f32
    __bf16* __restrict__ ctx)          // (b,640,256), channel = h*32+dh
{
    __shared__ __align__(16) __bf16 P[2][2][64][44];   // [wave][buf][i][j] 22.5 KB
    __shared__ float ssum[2][64];
    int bh = blockIdx.x, b = bh >> 3, h = bh & 7;
    int tid = threadIdx.x, w = tid >> 6, lane = tid & 63;
    int quad = lane >> 4, l15 = lane & 15;
    int i0 = (blockIdx.y * 2 + w) * 64;

    bf16x8 qa[4];
    #pragma unroll
    for (int m = 0; m < 4; ++m)
        qa[m] = *(const bf16x8*)(Q + ((size_t)bh * 640 + i0 + 16 * m + l15) * 32 + quad * 8);
    const __bf16* kbase = Km + (size_t)bh * 640 * 32 + quad * 8;
    const __bf16* vbase = Vt + ((size_t)bh * 32 + l15) * 640 + quad * 8;
    const float*  bcb   = biasF + (size_t)(h * 40 + (i0 >> 4)) * 10240 + lane * 8;

    f32x4 o[4][2] = {};
    float psum[4] = {0.f, 0.f, 0.f, 0.f};

    // preload chunk 0 K + bias (bias = f32 C-fragments, two f32x4 per m)
    bf16x8 k0 = *(const bf16x8*)(kbase + (size_t)l15 * 32);
    bf16x8 k1 = *(const bf16x8*)(kbase + (size_t)(16 + l15) * 32);
    f32x4 bc[4][2];
    #pragma unroll
    for (int m = 0; m < 4; ++m) {
        bc[m][0] = *(const f32x4*)(bcb + m * 10240);
        bc[m][1] = *(const f32x4*)(bcb + m * 10240 + 4);
    }
    bf16x8 vC0 = {}, vC1 = {};

    for (int c = 0; c < 20; ++c) {
        int buf = c & 1;
        // ---- S-MFMAs for chunk c (K/bias already resident; bias IS the C input) ----
        f32x4 s[4][2];
        __builtin_amdgcn_s_setprio(1);
        #pragma unroll
        for (int m = 0; m < 4; ++m) {
            s[m][0] = __builtin_amdgcn_mfma_f32_16x16x32_bf16(k0, qa[m], bc[m][0], 0, 0, 0);
            s[m][1] = __builtin_amdgcn_mfma_f32_16x16x32_bf16(k1, qa[m], bc[m][1], 0, 0, 0);
        }
        __builtin_amdgcn_s_setprio(0);
        // ---- issue prefetches: K/bias for c+1, V for c ----
        int cn = min(c + 1, 19);
        bf16x8 k0n = *(const bf16x8*)(kbase + (size_t)(cn * 32 + l15) * 32);
        bf16x8 k1n = *(const bf16x8*)(kbase + (size_t)(cn * 32 + 16 + l15) * 32);
        bf16x8 vN0 = *(const bf16x8*)(vbase + c * 32);
        bf16x8 vN1 = *(const bf16x8*)(vbase + (size_t)16 * 640 + c * 32);
        f32x4 bn[4][2];
        #pragma unroll
        for (int m = 0; m < 4; ++m) {
            bn[m][0] = *(const f32x4*)(bcb + m * 10240 + cn * 512);
            bn[m][1] = *(const f32x4*)(bcb + m * 10240 + cn * 512 + 4);
        }
        // ---- exp/pack for chunk c (held in regs) ----
        bf16x4 pk[4][2];
        #pragma unroll
        for (int m = 0; m < 4; ++m) {
            #pragma unroll
            for (int rr = 0; rr < 4; ++rr) {
                float e0 = fast_exp2(s[m][0][rr]); psum[m] += e0; pk[m][0][rr] = (__bf16)e0;
                float e1 = fast_exp2(s[m][1][rr]); psum[m] += e1; pk[m][1][rr] = (__bf16)e1;
            }
        }
        // ---- PV for chunk c-1 (P written one full iteration ago) ----
        if (c > 0) {
            __builtin_amdgcn_s_setprio(1);
            #pragma unroll
            for (int m = 0; m < 4; ++m) {
                bf16x8 pa = *(const bf16x8*)(&P[w][buf ^ 1][16 * m + l15][quad * 8]);
                o[m][0] = __builtin_amdgcn_mfma_f32_16x16x32_bf16(pa, vC0, o[m][0], 0, 0, 0);
                o[m][1] = __builtin_amdgcn_mfma_f32_16x16x32_bf16(pa, vC1, o[m][1], 0, 0, 0);
            }
            __builtin_amdgcn_s_setprio(0);
        }
        // ---- write P(c) (read next iteration) ----
        #pragma unroll
        for (int m = 0; m < 4; ++m) {
            *(bf16x4*)(&P[w][buf][16 * m + l15][quad * 4])      = pk[m][0];
            *(bf16x4*)(&P[w][buf][16 * m + l15][16 + quad * 4]) = pk[m][1];
        }
        k0 = k0n; k1 = k1n; vC0 = vN0; vC1 = vN1;
        #pragma unroll
        for (int m = 0; m < 4; ++m) { bc[m][0] = bn[m][0]; bc[m][1] = bn[m][1]; }
    }
    // final PV (chunk 19, buf 1)
    __builtin_amdgcn_s_setprio(1);
    #pragma unroll
    for (int m = 0; m < 4; ++m) {
        bf16x8 pa = *(const bf16x8*)(&P[w][1][16 * m + l15][quad * 8]);
        o[m][0] = __builtin_amdgcn_mfma_f32_16x16x32_bf16(pa, vC0, o[m][0], 0, 0, 0);
        o[m][1] = __builtin_amdgcn_mfma_f32_16x16x32_bf16(pa, vC1, o[m][1], 0, 0, 0);
    }
    __builtin_amdgcn_s_setprio(0);

    // row sums: i lane-resident; reduce over quads
    #pragma unroll
    for (int m = 0; m < 4; ++m) {
        psum[m] += __shfl_xor(psum[m], 16);
        psum[m] += __shfl_xor(psum[m], 32);
    }
    if (quad == 0)
        #pragma unroll
        for (int m = 0; m < 4; ++m) ssum[w][16 * m + l15] = psum[m];
    #pragma unroll
    for (int m = 0; m < 4; ++m) {
        #pragma unroll
        for (int rr = 0; rr < 4; ++rr) {
            int il = 16 * m + quad * 4 + rr;
            float inv = 1.f / ssum[w][il];
            size_t base = ((size_t)b * 640 + i0 + il) * 256 + h * 32;
            ctx[base + l15]      = (__bf16)(o[m][0][rr] * inv);
            ctx[base + 16 + l15] = (__bf16)(o[m][1][rr] * inv);
        }
    }
}

// -------- output projection, LDS-staged 64x256 tile, BK=32; transposed store ----------
__global__ __launch_bounds__(256, 2) void k_outproj(
    const __bf16* __restrict__ ctx,   // (b,640,256)
    const __bf16* __restrict__ WoT,   // (256,256)
    const void* __restrict__ xorig,   // dtype sniff only
    void* __restrict__ out)           // (b,256,625)
{
    __shared__ __align__(16) __bf16 As2[64][40];
    __shared__ __align__(16) __bf16 Bs2[256][40];
    int isbf = sniff_isbf(xorig);
    int b = blockIdx.y, pt = blockIdx.x;
    int p0 = pt * 64;
    int tid = threadIdx.x, w = tid >> 6, lane = tid & 63;
    int quad = lane >> 4, l15 = lane & 15;
    int srow = tid >> 2, scg = (tid & 3) * 8;
    const __bf16* ag = ctx + ((size_t)(b * 640 + p0 + srow) * 256) + scg;
    const __bf16* bg = WoT + (size_t)srow * 256 + scg;

    f32x4 acc[4][4] = {};
    for (int kk = 0; kk < 8; ++kk) {
        int c0 = kk * 32;
        bf16x8 a0 = *(const bf16x8*)(ag + c0);
        bf16x8 b0 = *(const bf16x8*)(bg + c0);
        bf16x8 b1 = *(const bf16x8*)(bg + 64 * 256 + c0);
        bf16x8 b2 = *(const bf16x8*)(bg + 128 * 256 + c0);
        bf16x8 b3 = *(const bf16x8*)(bg + 192 * 256 + c0);
        __syncthreads();
        *(bf16x8*)(&As2[srow][scg])       = a0;
        *(bf16x8*)(&Bs2[srow][scg])       = b0;
        *(bf16x8*)(&Bs2[64 + srow][scg])  = b1;
        *(bf16x8*)(&Bs2[128 + srow][scg]) = b2;
        *(bf16x8*)(&Bs2[192 + srow][scg]) = b3;
        __syncthreads();
        bf16x8 af[4], bfr[4];
        #pragma unroll
        for (int t = 0; t < 4; ++t) {
            af[t]  = *(const bf16x8*)(&As2[t * 16 + l15][quad * 8]);
            bfr[t] = *(const bf16x8*)(&Bs2[w * 64 + t * 16 + l15][quad * 8]);
        }
        #pragma unroll
        for (int i = 0; i < 4; ++i)
            #pragma unroll
            for (int j = 0; j < 4; ++j)
                acc[i][j] = __builtin_amdgcn_mfma_f32_16x16x32_bf16(af[i], bfr[j], acc[i][j], 0, 0, 0);
    }
    __bf16* outb = (__bf16*)out;
    float*  outf = (float*)out;
    #pragma unroll
    for (int i = 0; i < 4; ++i) {
        #pragma unroll
        for (int j = 0; j < 4; ++j) {
            int co = w * 64 + j * 16 + l15;
            #pragma unroll
            for (int rr = 0; rr < 4; ++rr) {
                int p = p0 + i * 16 + quad * 4 + rr;
                if (p < 625) {
                    size_t o = ((size_t)(b * 256) + co) * 625 + p;
                    if (isbf) outb[o] = (__bf16)acc[i][j][rr];
                    else      outf[o] = acc[i][j][rr];
                }
            }
        }
    }
}

extern "C" void kernel_launch(void* const* d_in, const int* in_sizes, int n_in,
                              void* d_out, int out_size, void* d_ws, size_t ws_size,
                              hipStream_t stream)
{
    const void* x    = d_in[0];
    const void* Wqkv = d_in[1];
    const void* Wout = d_in[2];
    const void* rel  = d_in[3];

    // ws layout, NO aliasing (ws_size is 256 MiB per the harness fill; we use ~83 MB).
    __bf16* ws    = (__bf16*)d_ws;
    __bf16* xT    = ws;                      // 10,485,760 bf16
    __bf16* Wt    = xT + 10485760;           //    196,608
    __bf16* WoT   = Wt + 196608;             //     65,536
    __bf16* Q     = WoT + 65536;             //  5,242,880
    __bf16* Km    = Q + 5242880;             //  5,242,880
    __bf16* Vt    = Km + 5242880;            //  5,242,880
    float*  biasF = (float*)(Vt + 5242880);  //  3,276,800 f32 (13.1 MB)
    __bf16* ctx   = (__bf16*)(biasF + 3276800); // 5,242,880 bf16

    k_pre<<<1664, 256, 0, stream>>>(x, Wqkv, Wout, rel, xT, Wt, WoT, biasF);
    k_qkv<<<dim3(960), 256, 0, stream>>>(xT, Wt, Q, Km, Vt);
    k_attn<<<dim3(256, 5), 128, 0, stream>>>(Q, Km, Vt, biasF, ctx);
    k_outproj<<<dim3(10, 32), 256, 0, stream>>>(ctx, WoT, x, d_out);
}

// Round 7
// 155.446 us; speedup vs baseline: 1.2601x; 1.0680x over previous
//
#include <hip/hip_runtime.h>
#include <hip/hip_bf16.h>
#include <cstdint>

typedef __bf16 bf16x8 __attribute__((ext_vector_type(8)));
typedef __bf16 bf16x4 __attribute__((ext_vector_type(4)));
typedef float  f32x4  __attribute__((ext_vector_type(4)));

__device__ __forceinline__ int div25(int v) { return (v * 1311) >> 15; }  // exact for v <= 1310

#if __has_builtin(__builtin_amdgcn_exp2f)
__device__ __forceinline__ float fast_exp2(float x) { return __builtin_amdgcn_exp2f(x); }
#else
__device__ __forceinline__ float fast_exp2(float x) { return exp2f(x); }
#endif

// async global->LDS, 16B per lane; dest must be wave-uniform base + lane*16 (linear)
__device__ __forceinline__ void gll16(const __bf16* g, __bf16* l)
{
    __builtin_amdgcn_global_load_lds(
        (__attribute__((address_space(1))) void*)(g),
        (__attribute__((address_space(3))) void*)(l),
        16, 0, 0);
}

// ---- inline dtype sniff: 16 uniform halfwords from one cache line ----
__device__ __forceinline__ int sniff_isbf(const void* p)
{
    const unsigned short* x = (const unsigned short*)p;
    int cnt = 0;
    #pragma unroll
    for (int i = 0; i < 16; ++i) {
        int e = (x[2 * i] >> 7) & 0xFF;
        cnt += (e >= 90 && e <= 143) ? 1 : 0;
    }
    return cnt > 8;
}

// ================= fused preprocessing: one launch, 3 independent jobs =================
// blocks [0,1280): x transpose+cvt  (b,256,625)->xT (b,640,256), pad rows zeroed
// blocks [1280,1344): weight prep   Wqkv/Wout -> Wt/WoT (transposed, qscale*log2e folded)
// blocks [1344,1664): bias table, packed bf16: biasC[((h*40+ig)*20+jc)*512 + lane*8 + js*4 + rr]
__global__ __launch_bounds__(256) void k_pre(
    const void* __restrict__ x, const void* __restrict__ Wqkv,
    const void* __restrict__ Wout, const void* __restrict__ rel,
    __bf16* __restrict__ xT, __bf16* __restrict__ Wt, __bf16* __restrict__ WoT,
    __bf16* __restrict__ biasC)
{
    __shared__ float tile[64][65];
    int bid = blockIdx.x;
    if (bid < 1280) {
        // ---- x transpose ----
        int isbf = sniff_isbf(x);
        int b = bid / 40, rem = bid % 40;
        int c0 = (rem % 10) * 64, r0 = (rem / 10) * 64;
        const int R = 256, C = 625, Cpad = 640;
        int tc = threadIdx.x & 63, tg = threadIdx.x >> 6;
        const unsigned short* sb = (const unsigned short*)x + (size_t)b * (256 * 625);
        const float*          sf = (const float*)x          + (size_t)b * (256 * 625);
        #pragma unroll
        for (int rr = 0; rr < 16; ++rr) {
            int r = r0 + tg * 16 + rr, c = c0 + tc;
            float v = 0.f;
            if (r < R && c < C) {
                if (isbf) v = __uint_as_float((unsigned int)sb[r * C + c] << 16);
                else      v = sf[r * C + c];
            }
            tile[tg * 16 + rr][tc] = v;
        }
        __syncthreads();
        __bf16* d = xT + (size_t)b * (640 * 256);
        #pragma unroll
        for (int rr = 0; rr < 16; ++rr) {
            int c = c0 + tg * 16 + rr, r = r0 + tc;
            if (c < Cpad && r < R) d[(size_t)c * R + r] = (__bf16)tile[tc][tg * 16 + rr];
        }
    } else if (bid < 1344) {
        // ---- weight prep ----
        int q = bid - 1280;
        int bx = q % 16, by = q / 16;
        int isbf = sniff_isbf(Wqkv);
        int isqkv = (bx < 12);
        int bxx = isqkv ? bx : (bx - 12);
        const void* src = isqkv ? Wqkv : Wout;
        __bf16* dst = isqkv ? Wt : WoT;
        int R = 256, C = isqkv ? 768 : 256;
        int r0 = by * 64, c0 = bxx * 64;
        int tc = threadIdx.x & 63, tg = threadIdx.x >> 6;
        const unsigned short* sb = (const unsigned short*)src;
        const float*          sf = (const float*)src;
        #pragma unroll
        for (int rr = 0; rr < 16; ++rr) {
            int r = r0 + tg * 16 + rr, c = c0 + tc;
            float v;
            if (isbf) v = __uint_as_float((unsigned int)sb[r * C + c] << 16);
            else      v = sf[r * C + c];
            tile[tg * 16 + rr][tc] = v;
        }
        __syncthreads();
        const float qs = 0.25503494f;  // 32^-0.5 * log2(e)
        #pragma unroll
        for (int rr = 0; rr < 16; ++rr) {
            int c = c0 + tg * 16 + rr, r = r0 + tc;
            float v = tile[tc][tg * 16 + rr];
            if (isqkv && c < 256) v *= qs;
            dst[(size_t)c * R + r] = (__bf16)v;
        }
    } else {
        // ---- bias table (packed per-lane layout, bf16) ----
        const float LOG2E = 1.4426950408889634f;
        int isbf = sniff_isbf(rel);
        int q = bid - 1344;
        int ig = q % 40, h = q / 40;
        for (int t0 = 0; t0 < 10; ++t0) {
            int t  = t0 * 256 + threadIdx.x;
            int jc = t >> 7;
            int js = (t >> 6) & 1;
            int ln = t & 63;
            int qd = ln >> 4, l = ln & 15;
            int i = ig * 16 + l;
            int di = div25(i), ri = i - 25 * di;
            bf16x4 out;
            #pragma unroll
            for (int rr = 0; rr < 4; ++rr) {
                int j = jc * 32 + js * 16 + qd * 4 + rr;
                float v;
                if (j >= 625) {
                    v = -43281.f;
                } else {
                    int dj = div25(j);
                    int idx = (di - dj + 24) * 49 + ri - (j - 25 * dj) + 24;
                    idx = min(max(idx, 0), 2400);
                    float r;
                    if (isbf) r = (float)((const __bf16*)rel)[idx * 8 + h];
                    else      r = ((const float*)rel)[idx * 8 + h];
                    v = r * LOG2E;
                }
                out[rr] = (__bf16)v;
            }
            *(bf16x4*)(biasC + ((size_t)(h * 40 + ig) * 20 + jc) * 512 + ln * 8 + js * 4) = out;
        }
    }
}

// -------- QKV projection, 128x128 tile, BK=32, 2-phase double-buffered gll16 ----------
// T3-minimum pipeline: STAGE(kk+1 -> buf^1) issued BEFORE compute(kk); ONE barrier/step.
// Load latency hides under 16 MFMAs + 8 ds_reads. LDS 32KB staging, CS overlays buf0.
#define AS(bf, r, c) pool[(size_t)(bf) * 8192 + (size_t)(r) * 32 + (c)]
#define BS(bf, r, c) pool[(size_t)(bf) * 8192 + 4096 + (size_t)(r) * 32 + (c)]
#define CS(r, c)     pool[(size_t)(r) * 44 + (c)]
__global__ __launch_bounds__(256, 2) void k_qkv(
    const __bf16* __restrict__ xT,   // (b,640,256), pad rows zeroed
    const __bf16* __restrict__ Wt,   // (768,256)
    __bf16* __restrict__ Q,          // (b,8,640,32) scaled by 32^-.5*log2e
    __bf16* __restrict__ Km,         // (b,8,640,32)
    __bf16* __restrict__ Vt)         // (b,8,32,640)
{
    __shared__ __align__(16) __bf16 pool[16384];
    // XCD swizzle: L%8 = XCD (round-robin). 960 = 8 XCD * 20 pairs * 6 jt.
    int L = blockIdx.x;
    int xcd = L & 7;
    int cc  = L >> 3;                 // 0..119 within XCD
    int pairIdx = xcd * 20 + cc / 6;  // 0..159 = (b,pt) pair
    int jt = cc - (cc / 6) * 6;
    int b  = pairIdx / 5;
    int pt = pairIdx - b * 5;
    int p0 = pt * 128, j0 = jt * 128;
    int tid = threadIdx.x;
    int w = tid >> 6, lane = tid & 63;
    int quad = lane >> 4, l15 = lane & 15;
    int wr = w >> 1, wc = w & 1;

    int srow = tid >> 2, scg = (tid & 3) * 8;
    const __bf16* ag  = xT + ((size_t)(b * 640 + p0 + srow) * 256) + scg;
    const __bf16* ag2 = ag + 64 * 256;
    const __bf16* bg  = Wt + ((size_t)(j0 + srow) * 256) + scg;
    const __bf16* bg2 = bg + 64 * 256;

    // prologue: stage kk=0 into buf 0
    gll16(ag,  &AS(0, srow, scg));
    gll16(ag2, &AS(0, 64 + srow, scg));
    gll16(bg,  &BS(0, srow, scg));
    gll16(bg2, &BS(0, 64 + srow, scg));
    __syncthreads();   // vmcnt(0) drain + barrier

    f32x4 acc[4][4] = {};
    for (int kk = 0; kk < 8; ++kk) {
        int cur = kk & 1;
        if (kk < 7) {
            int c0 = (kk + 1) * 32;
            int nb = cur ^ 1;
            gll16(ag  + c0, &AS(nb, srow, scg));
            gll16(ag2 + c0, &AS(nb, 64 + srow, scg));
            gll16(bg  + c0, &BS(nb, srow, scg));
            gll16(bg2 + c0, &BS(nb, 64 + srow, scg));
        }
        bf16x8 af[4], bfr[4];
        #pragma unroll
        for (int t = 0; t < 4; ++t) {
            af[t]  = *(const bf16x8*)(&AS(cur, wr * 64 + t * 16 + l15, quad * 8));
            bfr[t] = *(const bf16x8*)(&BS(cur, wc * 64 + t * 16 + l15, quad * 8));
        }
        #pragma unroll
        for (int i = 0; i < 4; ++i)
            #pragma unroll
            for (int j = 0; j < 4; ++j)
                acc[i][j] = __builtin_amdgcn_mfma_f32_16x16x32_bf16(af[i], bfr[j], acc[i][j], 0, 0, 0);
        __syncthreads();   // drains stage(kk+1); protects buf^1 overwrite at kk+2
    }

    if (jt < 4) {
        for (int r = 0; r < 4; ++r) {
            __syncthreads();
            if (wc == (r >> 1)) {
                #pragma unroll
                for (int i = 0; i < 4; ++i) {
                    #pragma unroll
                    for (int js = 0; js < 2; ++js) {
                        int jp = (r & 1) * 2 + js;
                        int col = js * 16 + l15;
                        int prow = wr * 64 + i * 16 + quad * 4;
                        #pragma unroll
                        for (int rr = 0; rr < 4; ++rr)
                            CS(prow + rr, col) = (__bf16)acc[i][jp][rr];
                    }
                }
            }
            __syncthreads();
            int jj = j0 + r * 32;
            __bf16* dst; int hh;
            if (jj < 256) { hh = jj >> 5; dst = Q; }
            else          { hh = (jj - 256) >> 5; dst = Km; }
            int p = tid >> 1, d0 = (tid & 1) * 16;
            size_t base = ((size_t)((b * 8 + hh) * 640) + p0 + p) * 32 + d0;
            #pragma unroll
            for (int k4 = 0; k4 < 4; ++k4) {
                bf16x4 v4 = *(const bf16x4*)(&CS(p, d0 + k4 * 4));
                *(bf16x4*)(dst + base + k4 * 4) = v4;
            }
        }
    } else {
        #pragma unroll
        for (int i = 0; i < 4; ++i) {
            #pragma unroll
            for (int j = 0; j < 4; ++j) {
                int jj = j0 + wc * 64 + j * 16 + l15 - 512;
                int h = jj >> 5, t = jj & 31;
                int p = p0 + wr * 64 + i * 16 + quad * 4;
                bf16x4 vv;
                #pragma unroll
                for (int rr = 0; rr < 4; ++rr) vv[rr] = (__bf16)acc[i][j][rr];
                *(bf16x4*)(Vt + ((size_t)((b * 8 + h) * 32) + t) * 640 + p) = vv;
            }
        }
    }
}

// -------- fused attention v11 (R4-verified best: total 157.4, dur <=42) --------------
// 64-row waves, grid 256x5, P stride 44, depth-1 prefetch, packed bf16 bias.
__global__ __launch_bounds__(128, 3) void k_attn(
    const __bf16* __restrict__ Q,
    const __bf16* __restrict__ Km,
    const __bf16* __restrict__ Vt,
    const __bf16* __restrict__ biasC,  // packed C-fragment order, *log2e
    __bf16* __restrict__ ctx)          // (b,640,256), channel = h*32+dh
{
    __shared__ __align__(16) __bf16 P[2][2][64][44];   // [wave][buf][i][j] 22.5 KB
    __shared__ float ssum[2][64];
    int bh = blockIdx.x, b = bh >> 3, h = bh & 7;
    int tid = threadIdx.x, w = tid >> 6, lane = tid & 63;
    int quad = lane >> 4, l15 = lane & 15;
    int i0 = (blockIdx.y * 2 + w) * 64;

    bf16x8 qa[4];
    #pragma unroll
    for (int m = 0; m < 4; ++m)
        qa[m] = *(const bf16x8*)(Q + ((size_t)bh * 640 + i0 + 16 * m + l15) * 32 + quad * 8);
    const __bf16* kbase = Km + (size_t)bh * 640 * 32 + quad * 8;
    const __bf16* vbase = Vt + ((size_t)bh * 32 + l15) * 640 + quad * 8;
    const __bf16* bcb   = biasC + (size_t)(h * 40 + (i0 >> 4)) * 10240 + lane * 8;

    f32x4 o[4][2] = {};
    float psum[4] = {0.f, 0.f, 0.f, 0.f};

    // preload chunk 0 K + bias
    bf16x8 k0 = *(const bf16x8*)(kbase + (size_t)l15 * 32);
    bf16x8 k1 = *(const bf16x8*)(kbase + (size_t)(16 + l15) * 32);
    bf16x8 bc[4];
    #pragma unroll
    for (int m = 0; m < 4; ++m)
        bc[m] = *(const bf16x8*)(bcb + m * 10240);
    bf16x8 vC0 = {}, vC1 = {};

    for (int c = 0; c < 20; ++c) {
        int buf = c & 1;
        // ---- S-MFMAs for chunk c (K/bias already resident) ----
        f32x4 s[4][2];
        __builtin_amdgcn_s_setprio(1);
        #pragma unroll
        for (int m = 0; m < 4; ++m) {
            f32x4 f0, f1;
            #pragma unroll
            for (int rr = 0; rr < 4; ++rr) { f0[rr] = (float)bc[m][rr]; f1[rr] = (float)bc[m][4 + rr]; }
            s[m][0] = __builtin_amdgcn_mfma_f32_16x16x32_bf16(k0, qa[m], f0, 0, 0, 0);
            s[m][1] = __builtin_amdgcn_mfma_f32_16x16x32_bf16(k1, qa[m], f1, 0, 0, 0);
        }
        __builtin_amdgcn_s_setprio(0);
        // ---- issue prefetches: K/bias for c+1, V for c ----
        int cn = min(c + 1, 19);
        bf16x8 k0n = *(const bf16x8*)(kbase + (size_t)(cn * 32 + l15) * 32);
        bf16x8 k1n = *(const bf16x8*)(kbase + (size_t)(cn * 32 + 16 + l15) * 32);
        bf16x8 vN0 = *(const bf16x8*)(vbase + c * 32);
        bf16x8 vN1 = *(const bf16x8*)(vbase + (size_t)16 * 640 + c * 32);
        bf16x8 bn[4];
        #pragma unroll
        for (int m = 0; m < 4; ++m)
            bn[m] = *(const bf16x8*)(bcb + m * 10240 + cn * 512);
        // ---- exp/pack for chunk c (held in regs) ----
        bf16x4 pk[4][2];
        #pragma unroll
        for (int m = 0; m < 4; ++m) {
            #pragma unroll
            for (int rr = 0; rr < 4; ++rr) {
                float e0 = fast_exp2(s[m][0][rr]); psum[m] += e0; pk[m][0][rr] = (__bf16)e0;
                float e1 = fast_exp2(s[m][1][rr]); psum[m] += e1; pk[m][1][rr] = (__bf16)e1;
            }
        }
        // ---- PV for chunk c-1 (P written one full iteration ago) ----
        if (c > 0) {
            __builtin_amdgcn_s_setprio(1);
            #pragma unroll
            for (int m = 0; m < 4; ++m) {
                bf16x8 pa = *(const bf16x8*)(&P[w][buf ^ 1][16 * m + l15][quad * 8]);
                o[m][0] = __builtin_amdgcn_mfma_f32_16x16x32_bf16(pa, vC0, o[m][0], 0, 0, 0);
                o[m][1] = __builtin_amdgcn_mfma_f32_16x16x32_bf16(pa, vC1, o[m][1], 0, 0, 0);
            }
            __builtin_amdgcn_s_setprio(0);
        }
        // ---- write P(c) (read next iteration) ----
        #pragma unroll
        for (int m = 0; m < 4; ++m) {
            *(bf16x4*)(&P[w][buf][16 * m + l15][quad * 4])      = pk[m][0];
            *(bf16x4*)(&P[w][buf][16 * m + l15][16 + quad * 4]) = pk[m][1];
        }
        k0 = k0n; k1 = k1n; vC0 = vN0; vC1 = vN1;
        #pragma unroll
        for (int m = 0; m < 4; ++m) bc[m] = bn[m];
    }
    // final PV (chunk 19, buf 1)
    __builtin_amdgcn_s_setprio(1);
    #pragma unroll
    for (int m = 0; m < 4; ++m) {
        bf16x8 pa = *(const bf16x8*)(&P[w][1][16 * m + l15][quad * 8]);
        o[m][0] = __builtin_amdgcn_mfma_f32_16x16x32_bf16(pa, vC0, o[m][0], 0, 0, 0);
        o[m][1] = __builtin_amdgcn_mfma_f32_16x16x32_bf16(pa, vC1, o[m][1], 0, 0, 0);
    }
    __builtin_amdgcn_s_setprio(0);

    // row sums: i lane-resident; reduce over quads
    #pragma unroll
    for (int m = 0; m < 4; ++m) {
        psum[m] += __shfl_xor(psum[m], 16);
        psum[m] += __shfl_xor(psum[m], 32);
    }
    if (quad == 0)
        #pragma unroll
        for (int m = 0; m < 4; ++m) ssum[w][16 * m + l15] = psum[m];
    #pragma unroll
    for (int m = 0; m < 4; ++m) {
        #pragma unroll
        for (int rr = 0; rr < 4; ++rr) {
            int il = 16 * m + quad * 4 + rr;
            float inv = 1.f / ssum[w][il];
            size_t base = ((size_t)b * 640 + i0 + il) * 256 + h * 32;
            ctx[base + l15]      = (__bf16)(o[m][0][rr] * inv);
            ctx[base + 16 + l15] = (__bf16)(o[m][1][rr] * inv);
        }
    }
}

// -------- output projection, 64x256 tile, BK=32, 2-phase double-buffered gll16 --------
// Same T3-minimum pipeline as k_qkv: stage kk+1 before compute kk, one barrier/step.
// Per buf: A 64x32 (2048) + B 256x32 (8192) = 10240 elems; 2 bufs = 40KB, 2 blocks/CU.
__global__ __launch_bounds__(256, 2) void k_outproj(
    const __bf16* __restrict__ ctx,   // (b,640,256)
    const __bf16* __restrict__ WoT,   // (256,256)
    const void* __restrict__ xorig,   // dtype sniff only
    void* __restrict__ out)           // (b,256,625)
{
    __shared__ __align__(16) __bf16 pool2[20480];
    int isbf = sniff_isbf(xorig);
    int b = blockIdx.y, pt = blockIdx.x;
    int p0 = pt * 64;
    int tid = threadIdx.x, w = tid >> 6, lane = tid & 63;
    int quad = lane >> 4, l15 = lane & 15;
    int srow = tid >> 2, scg = (tid & 3) * 8;
    const __bf16* ag = ctx + ((size_t)(b * 640 + p0 + srow) * 256) + scg;
    const __bf16* bg = WoT + (size_t)srow * 256 + scg;

    // prologue: stage kk=0 into buf 0
    gll16(ag,            &pool2[(size_t)srow * 32 + scg]);
    gll16(bg,            &pool2[2048 + (size_t)srow * 32 + scg]);
    gll16(bg + 64 * 256, &pool2[2048 + (size_t)(64 + srow) * 32 + scg]);
    gll16(bg + 128 * 256,&pool2[2048 + (size_t)(128 + srow) * 32 + scg]);
    gll16(bg + 192 * 256,&pool2[2048 + (size_t)(192 + srow) * 32 + scg]);
    __syncthreads();

    f32x4 acc[4][4] = {};
    for (int kk = 0; kk < 8; ++kk) {
        int cur = kk & 1;
        size_t base = (size_t)cur * 10240;
        if (kk < 7) {
            int c0 = (kk + 1) * 32;
            size_t nb = (size_t)(cur ^ 1) * 10240;
            gll16(ag + c0,             &pool2[nb + (size_t)srow * 32 + scg]);
            gll16(bg + c0,             &pool2[nb + 2048 + (size_t)srow * 32 + scg]);
            gll16(bg + 64 * 256 + c0,  &pool2[nb + 2048 + (size_t)(64 + srow) * 32 + scg]);
            gll16(bg + 128 * 256 + c0, &pool2[nb + 2048 + (size_t)(128 + srow) * 32 + scg]);
            gll16(bg + 192 * 256 + c0, &pool2[nb + 2048 + (size_t)(192 + srow) * 32 + scg]);
        }
        bf16x8 af[4], bfr[4];
        #pragma unroll
        for (int t = 0; t < 4; ++t) {
            af[t]  = *(const bf16x8*)(&pool2[base + (size_t)(t * 16 + l15) * 32 + quad * 8]);
            bfr[t] = *(const bf16x8*)(&pool2[base + 2048 + (size_t)(w * 64 + t * 16 + l15) * 32 + quad * 8]);
        }
        #pragma unroll
        for (int i = 0; i < 4; ++i)
            #pragma unroll
            for (int j = 0; j < 4; ++j)
                acc[i][j] = __builtin_amdgcn_mfma_f32_16x16x32_bf16(af[i], bfr[j], acc[i][j], 0, 0, 0);
        __syncthreads();
    }
    __bf16* outb = (__bf16*)out;
    float*  outf = (float*)out;
    #pragma unroll
    for (int i = 0; i < 4; ++i) {
        #pragma unroll
        for (int j = 0; j < 4; ++j) {
            int co = w * 64 + j * 16 + l15;
            #pragma unroll
            for (int rr = 0; rr < 4; ++rr) {
                int p = p0 + i * 16 + quad * 4 + rr;
                if (p < 625) {
                    size_t o = ((size_t)(b * 256) + co) * 625 + p;
                    if (isbf) outb[o] = (__bf16)acc[i][j][rr];
                    else      outf[o] = acc[i][j][rr];
                }
            }
        }
    }
}

extern "C" void kernel_launch(void* const* d_in, const int* in_sizes, int n_in,
                              void* d_out, int out_size, void* d_ws, size_t ws_size,
                              hipStream_t stream)
{
    const void* x    = d_in[0];
    const void* Wqkv = d_in[1];
    const void* Wout = d_in[2];
    const void* rel  = d_in[3];

    // ws layout, NO aliasing (ws_size is 256 MiB per the harness fill; we use ~70 MB).
    __bf16* ws    = (__bf16*)d_ws;
    __bf16* xT    = ws;                      // 10,485,760 elems
    __bf16* Wt    = xT + 10485760;           //    196,608
    __bf16* WoT   = Wt + 196608;             //     65,536
    __bf16* Q     = WoT + 65536;             //  5,242,880
    __bf16* Km    = Q + 5242880;             //  5,242,880
    __bf16* Vt    = Km + 5242880;            //  5,242,880
    __bf16* biasC = Vt + 5242880;            //  3,276,800
    __bf16* ctx   = biasC + 3276800;         //  5,242,880   (total ~70 MB)

    k_pre<<<1664, 256, 0, stream>>>(x, Wqkv, Wout, rel, xT, Wt, WoT, biasC);
    k_qkv<<<dim3(960), 256, 0, stream>>>(xT, Wt, Q, Km, Vt);
    k_attn<<<dim3(256, 5), 128, 0, stream>>>(Q, Km, Vt, biasC, ctx);
    k_outproj<<<dim3(10, 32), 256, 0, stream>>>(ctx, WoT, x, d_out);
}

// Round 8
// 147.499 us; speedup vs baseline: 1.3280x; 1.0539x over previous
//
#include <hip/hip_runtime.h>
#include <hip/hip_bf16.h>
#include <cstdint>

typedef __bf16 bf16x8 __attribute__((ext_vector_type(8)));
typedef __bf16 bf16x4 __attribute__((ext_vector_type(4)));
typedef float  f32x4  __attribute__((ext_vector_type(4)));
typedef float  f32x4u __attribute__((ext_vector_type(4), aligned(4)));   // 4B-aligned vec load/store
typedef __bf16 bf16x4u __attribute__((ext_vector_type(4), aligned(2)));
typedef unsigned short u16x4 __attribute__((ext_vector_type(4), aligned(2)));

__device__ __forceinline__ int div25(int v) { return (v * 1311) >> 15; }  // exact for v <= 1310

#if __has_builtin(__builtin_amdgcn_exp2f)
__device__ __forceinline__ float fast_exp2(float x) { return __builtin_amdgcn_exp2f(x); }
#else
__device__ __forceinline__ float fast_exp2(float x) { return exp2f(x); }
#endif

// async global->LDS, 16B per lane; dest must be wave-uniform base + lane*16 (linear)
__device__ __forceinline__ void gll16(const __bf16* g, __bf16* l)
{
    __builtin_amdgcn_global_load_lds(
        (__attribute__((address_space(1))) void*)(g),
        (__attribute__((address_space(3))) void*)(l),
        16, 0, 0);
}

// ---- inline dtype sniff: 16 uniform halfwords from one cache line ----
__device__ __forceinline__ int sniff_isbf(const void* p)
{
    const unsigned short* x = (const unsigned short*)p;
    int cnt = 0;
    #pragma unroll
    for (int i = 0; i < 16; ++i) {
        int e = (x[2 * i] >> 7) & 0xFF;
        cnt += (e >= 90 && e <= 143) ? 1 : 0;
    }
    return cnt > 8;
}

// ================= fused preprocessing: one launch, 3 independent jobs =================
// blocks [0,1280): x transpose+cvt, VECTORIZED (f32x4 loads, bf16x4 stores)
// blocks [1280,1344): weight prep (unchanged, own 65-stride view of the shared pool)
// blocks [1344,1664): bias table, packed bf16 (unchanged)
__global__ __launch_bounds__(256) void k_pre(
    const void* __restrict__ x, const void* __restrict__ Wqkv,
    const void* __restrict__ Wout, const void* __restrict__ rel,
    __bf16* __restrict__ xT, __bf16* __restrict__ Wt, __bf16* __restrict__ WoT,
    __bf16* __restrict__ biasC)
{
    __shared__ __align__(16) float shpool[64 * 68];   // 17.4 KB, shared by both tile users
    int bid = blockIdx.x;
    if (bid < 1280) {
        // ---- x transpose, vectorized ----
        float (*tile)[68] = (float(*)[68])shpool;     // stride 68: 16B-aligned rows
        int isbf = sniff_isbf(x);
        int b = bid / 40, rem = bid % 40;
        int c0 = (rem % 10) * 64, r0 = (rem / 10) * 64;
        const int R = 256, C = 625;
        int t = threadIdx.x;
        int lr4 = (t >> 4) * 4;    // 0..60
        int lc4 = (t & 15) * 4;    // 0..60
        const unsigned short* sb = (const unsigned short*)x + (size_t)b * (256 * 625);
        const float*          sf = (const float*)x          + (size_t)b * (256 * 625);
        #pragma unroll
        for (int rr = 0; rr < 4; ++rr) {
            int r = r0 + lr4 + rr;        // r0 in {0,64,128,192} -> always < 256
            int c = c0 + lc4;
            f32x4 v = {0.f, 0.f, 0.f, 0.f};
            if (c + 3 < C) {
                if (isbf) {
                    u16x4 u = *(const u16x4*)(sb + (size_t)r * C + c);
                    #pragma unroll
                    for (int j = 0; j < 4; ++j) v[j] = __uint_as_float((unsigned)u[j] << 16);
                } else {
                    v = *(const f32x4u*)(sf + (size_t)r * C + c);
                }
            } else {
                #pragma unroll
                for (int j = 0; j < 4; ++j) {
                    int cc2 = c + j;
                    if (cc2 < C) {
                        if (isbf) v[j] = __uint_as_float((unsigned)sb[(size_t)r * C + cc2] << 16);
                        else      v[j] = sf[(size_t)r * C + cc2];
                    }
                }
            }
            *(f32x4*)(&tile[lr4 + rr][lc4]) = v;      // 16B-aligned LDS store
        }
        __syncthreads();
        // write phase: lane group spans all 64 tile columns -> 2-way banks (free);
        // each thread emits 4x bf16x4 (vs 16x 2B scalar before).
        __bf16* d = xT + (size_t)b * (640 * 256);
        int lc = t & 63, rc = (t >> 6) * 16;
        int c = c0 + lc;                              // all c < 640 written (0 beyond 624)
        #pragma unroll
        for (int k = 0; k < 4; ++k) {
            bf16x4 o4;
            #pragma unroll
            for (int j = 0; j < 4; ++j) o4[j] = (__bf16)tile[rc + k * 4 + j][lc];
            *(bf16x4*)(d + (size_t)c * R + r0 + rc + k * 4) = o4;   // 8B-aligned
        }
    } else if (bid < 1344) {
        // ---- weight prep (unchanged; 65-stride view avoids its 8-way read conflict) ----
        float (*tile)[65] = (float(*)[65])shpool;
        int q = bid - 1280;
        int bx = q % 16, by = q / 16;
        int isbf = sniff_isbf(Wqkv);
        int isqkv = (bx < 12);
        int bxx = isqkv ? bx : (bx - 12);
        const void* src = isqkv ? Wqkv : Wout;
        __bf16* dst = isqkv ? Wt : WoT;
        int R = 256, C = isqkv ? 768 : 256;
        int r0 = by * 64, c0 = bxx * 64;
        int tc = threadIdx.x & 63, tg = threadIdx.x >> 6;
        const unsigned short* sb = (const unsigned short*)src;
        const float*          sf = (const float*)src;
        #pragma unroll
        for (int rr = 0; rr < 16; ++rr) {
            int r = r0 + tg * 16 + rr, c = c0 + tc;
            float v;
            if (isbf) v = __uint_as_float((unsigned int)sb[r * C + c] << 16);
            else      v = sf[r * C + c];
            tile[tg * 16 + rr][tc] = v;
        }
        __syncthreads();
        const float qs = 0.25503494f;  // 32^-0.5 * log2(e)
        #pragma unroll
        for (int rr = 0; rr < 16; ++rr) {
            int c = c0 + tg * 16 + rr, r = r0 + tc;
            float v = tile[tc][tg * 16 + rr];
            if (isqkv && c < 256) v *= qs;
            dst[(size_t)c * R + r] = (__bf16)v;
        }
    } else {
        // ---- bias table (packed per-lane layout, bf16) ----
        const float LOG2E = 1.4426950408889634f;
        int isbf = sniff_isbf(rel);
        int q = bid - 1344;
        int ig = q % 40, h = q / 40;
        for (int t0 = 0; t0 < 10; ++t0) {
            int t  = t0 * 256 + threadIdx.x;
            int jc = t >> 7;
            int js = (t >> 6) & 1;
            int ln = t & 63;
            int qd = ln >> 4, l = ln & 15;
            int i = ig * 16 + l;
            int di = div25(i), ri = i - 25 * di;
            bf16x4 out;
            #pragma unroll
            for (int rr = 0; rr < 4; ++rr) {
                int j = jc * 32 + js * 16 + qd * 4 + rr;
                float v;
                if (j >= 625) {
                    v = -43281.f;
                } else {
                    int dj = div25(j);
                    int idx = (di - dj + 24) * 49 + ri - (j - 25 * dj) + 24;
                    idx = min(max(idx, 0), 2400);
                    float r;
                    if (isbf) r = (float)((const __bf16*)rel)[idx * 8 + h];
                    else      r = ((const float*)rel)[idx * 8 + h];
                    v = r * LOG2E;
                }
                out[rr] = (__bf16)v;
            }
            *(bf16x4*)(biasC + ((size_t)(h * 40 + ig) * 20 + jc) * 512 + ln * 8 + js * 4) = out;
        }
    }
}

// -------- QKV projection, 128x128 tile, BK=32, 2-phase double-buffered gll16 ----------
// (byte-identical to R7, 155.4us best)
#define AS(bf, r, c) pool[(size_t)(bf) * 8192 + (size_t)(r) * 32 + (c)]
#define BS(bf, r, c) pool[(size_t)(bf) * 8192 + 4096 + (size_t)(r) * 32 + (c)]
#define CS(r, c)     pool[(size_t)(r) * 44 + (c)]
__global__ __launch_bounds__(256, 2) void k_qkv(
    const __bf16* __restrict__ xT,   // (b,640,256), pad rows zeroed
    const __bf16* __restrict__ Wt,   // (768,256)
    __bf16* __restrict__ Q,          // (b,8,640,32) scaled by 32^-.5*log2e
    __bf16* __restrict__ Km,         // (b,8,640,32)
    __bf16* __restrict__ Vt)         // (b,8,32,640)
{
    __shared__ __align__(16) __bf16 pool[16384];
    int L = blockIdx.x;
    int xcd = L & 7;
    int cc  = L >> 3;
    int pairIdx = xcd * 20 + cc / 6;
    int jt = cc - (cc / 6) * 6;
    int b  = pairIdx / 5;
    int pt = pairIdx - b * 5;
    int p0 = pt * 128, j0 = jt * 128;
    int tid = threadIdx.x;
    int w = tid >> 6, lane = tid & 63;
    int quad = lane >> 4, l15 = lane & 15;
    int wr = w >> 1, wc = w & 1;

    int srow = tid >> 2, scg = (tid & 3) * 8;
    const __bf16* ag  = xT + ((size_t)(b * 640 + p0 + srow) * 256) + scg;
    const __bf16* ag2 = ag + 64 * 256;
    const __bf16* bg  = Wt + ((size_t)(j0 + srow) * 256) + scg;
    const __bf16* bg2 = bg + 64 * 256;

    gll16(ag,  &AS(0, srow, scg));
    gll16(ag2, &AS(0, 64 + srow, scg));
    gll16(bg,  &BS(0, srow, scg));
    gll16(bg2, &BS(0, 64 + srow, scg));
    __syncthreads();

    f32x4 acc[4][4] = {};
    for (int kk = 0; kk < 8; ++kk) {
        int cur = kk & 1;
        if (kk < 7) {
            int c0 = (kk + 1) * 32;
            int nb = cur ^ 1;
            gll16(ag  + c0, &AS(nb, srow, scg));
            gll16(ag2 + c0, &AS(nb, 64 + srow, scg));
            gll16(bg  + c0, &BS(nb, srow, scg));
            gll16(bg2 + c0, &BS(nb, 64 + srow, scg));
        }
        bf16x8 af[4], bfr[4];
        #pragma unroll
        for (int t = 0; t < 4; ++t) {
            af[t]  = *(const bf16x8*)(&AS(cur, wr * 64 + t * 16 + l15, quad * 8));
            bfr[t] = *(const bf16x8*)(&BS(cur, wc * 64 + t * 16 + l15, quad * 8));
        }
        #pragma unroll
        for (int i = 0; i < 4; ++i)
            #pragma unroll
            for (int j = 0; j < 4; ++j)
                acc[i][j] = __builtin_amdgcn_mfma_f32_16x16x32_bf16(af[i], bfr[j], acc[i][j], 0, 0, 0);
        __syncthreads();
    }

    if (jt < 4) {
        for (int r = 0; r < 4; ++r) {
            __syncthreads();
            if (wc == (r >> 1)) {
                #pragma unroll
                for (int i = 0; i < 4; ++i) {
                    #pragma unroll
                    for (int js = 0; js < 2; ++js) {
                        int jp = (r & 1) * 2 + js;
                        int col = js * 16 + l15;
                        int prow = wr * 64 + i * 16 + quad * 4;
                        #pragma unroll
                        for (int rr = 0; rr < 4; ++rr)
                            CS(prow + rr, col) = (__bf16)acc[i][jp][rr];
                    }
                }
            }
            __syncthreads();
            int jj = j0 + r * 32;
            __bf16* dst; int hh;
            if (jj < 256) { hh = jj >> 5; dst = Q; }
            else          { hh = (jj - 256) >> 5; dst = Km; }
            int p = tid >> 1, d0 = (tid & 1) * 16;
            size_t base = ((size_t)((b * 8 + hh) * 640) + p0 + p) * 32 + d0;
            #pragma unroll
            for (int k4 = 0; k4 < 4; ++k4) {
                bf16x4 v4 = *(const bf16x4*)(&CS(p, d0 + k4 * 4));
                *(bf16x4*)(dst + base + k4 * 4) = v4;
            }
        }
    } else {
        #pragma unroll
        for (int i = 0; i < 4; ++i) {
            #pragma unroll
            for (int j = 0; j < 4; ++j) {
                int jj = j0 + wc * 64 + j * 16 + l15 - 512;
                int h = jj >> 5, t = jj & 31;
                int p = p0 + wr * 64 + i * 16 + quad * 4;
                bf16x4 vv;
                #pragma unroll
                for (int rr = 0; rr < 4; ++rr) vv[rr] = (__bf16)acc[i][j][rr];
                *(bf16x4*)(Vt + ((size_t)((b * 8 + h) * 32) + t) * 640 + p) = vv;
            }
        }
    }
}

// -------- fused attention v11 (verified best structure; byte-identical to R7) ---------
__global__ __launch_bounds__(128, 3) void k_attn(
    const __bf16* __restrict__ Q,
    const __bf16* __restrict__ Km,
    const __bf16* __restrict__ Vt,
    const __bf16* __restrict__ biasC,  // packed C-fragment order, *log2e
    __bf16* __restrict__ ctx)          // (b,640,256), channel = h*32+dh
{
    __shared__ __align__(16) __bf16 P[2][2][64][44];   // [wave][buf][i][j] 22.5 KB
    __shared__ float ssum[2][64];
    int bh = blockIdx.x, b = bh >> 3, h = bh & 7;
    int tid = threadIdx.x, w = tid >> 6, lane = tid & 63;
    int quad = lane >> 4, l15 = lane & 15;
    int i0 = (blockIdx.y * 2 + w) * 64;

    bf16x8 qa[4];
    #pragma unroll
    for (int m = 0; m < 4; ++m)
        qa[m] = *(const bf16x8*)(Q + ((size_t)bh * 640 + i0 + 16 * m + l15) * 32 + quad * 8);
    const __bf16* kbase = Km + (size_t)bh * 640 * 32 + quad * 8;
    const __bf16* vbase = Vt + ((size_t)bh * 32 + l15) * 640 + quad * 8;
    const __bf16* bcb   = biasC + (size_t)(h * 40 + (i0 >> 4)) * 10240 + lane * 8;

    f32x4 o[4][2] = {};
    float psum[4] = {0.f, 0.f, 0.f, 0.f};

    bf16x8 k0 = *(const bf16x8*)(kbase + (size_t)l15 * 32);
    bf16x8 k1 = *(const bf16x8*)(kbase + (size_t)(16 + l15) * 32);
    bf16x8 bc[4];
    #pragma unroll
    for (int m = 0; m < 4; ++m)
        bc[m] = *(const bf16x8*)(bcb + m * 10240);
    bf16x8 vC0 = {}, vC1 = {};

    for (int c = 0; c < 20; ++c) {
        int buf = c & 1;
        f32x4 s[4][2];
        __builtin_amdgcn_s_setprio(1);
        #pragma unroll
        for (int m = 0; m < 4; ++m) {
            f32x4 f0, f1;
            #pragma unroll
            for (int rr = 0; rr < 4; ++rr) { f0[rr] = (float)bc[m][rr]; f1[rr] = (float)bc[m][4 + rr]; }
            s[m][0] = __builtin_amdgcn_mfma_f32_16x16x32_bf16(k0, qa[m], f0, 0, 0, 0);
            s[m][1] = __builtin_amdgcn_mfma_f32_16x16x32_bf16(k1, qa[m], f1, 0, 0, 0);
        }
        __builtin_amdgcn_s_setprio(0);
        int cn = min(c + 1, 19);
        bf16x8 k0n = *(const bf16x8*)(kbase + (size_t)(cn * 32 + l15) * 32);
        bf16x8 k1n = *(const bf16x8*)(kbase + (size_t)(cn * 32 + 16 + l15) * 32);
        bf16x8 vN0 = *(const bf16x8*)(vbase + c * 32);
        bf16x8 vN1 = *(const bf16x8*)(vbase + (size_t)16 * 640 + c * 32);
        bf16x8 bn[4];
        #pragma unroll
        for (int m = 0; m < 4; ++m)
            bn[m] = *(const bf16x8*)(bcb + m * 10240 + cn * 512);
        bf16x4 pk[4][2];
        #pragma unroll
        for (int m = 0; m < 4; ++m) {
            #pragma unroll
            for (int rr = 0; rr < 4; ++rr) {
                float e0 = fast_exp2(s[m][0][rr]); psum[m] += e0; pk[m][0][rr] = (__bf16)e0;
                float e1 = fast_exp2(s[m][1][rr]); psum[m] += e1; pk[m][1][rr] = (__bf16)e1;
            }
        }
        if (c > 0) {
            __builtin_amdgcn_s_setprio(1);
            #pragma unroll
            for (int m = 0; m < 4; ++m) {
                bf16x8 pa = *(const bf16x8*)(&P[w][buf ^ 1][16 * m + l15][quad * 8]);
                o[m][0] = __builtin_amdgcn_mfma_f32_16x16x32_bf16(pa, vC0, o[m][0], 0, 0, 0);
                o[m][1] = __builtin_amdgcn_mfma_f32_16x16x32_bf16(pa, vC1, o[m][1], 0, 0, 0);
            }
            __builtin_amdgcn_s_setprio(0);
        }
        #pragma unroll
        for (int m = 0; m < 4; ++m) {
            *(bf16x4*)(&P[w][buf][16 * m + l15][quad * 4])      = pk[m][0];
            *(bf16x4*)(&P[w][buf][16 * m + l15][16 + quad * 4]) = pk[m][1];
        }
        k0 = k0n; k1 = k1n; vC0 = vN0; vC1 = vN1;
        #pragma unroll
        for (int m = 0; m < 4; ++m) bc[m] = bn[m];
    }
    __builtin_amdgcn_s_setprio(1);
    #pragma unroll
    for (int m = 0; m < 4; ++m) {
        bf16x8 pa = *(const bf16x8*)(&P[w][1][16 * m + l15][quad * 8]);
        o[m][0] = __builtin_amdgcn_mfma_f32_16x16x32_bf16(pa, vC0, o[m][0], 0, 0, 0);
        o[m][1] = __builtin_amdgcn_mfma_f32_16x16x32_bf16(pa, vC1, o[m][1], 0, 0, 0);
    }
    __builtin_amdgcn_s_setprio(0);

    #pragma unroll
    for (int m = 0; m < 4; ++m) {
        psum[m] += __shfl_xor(psum[m], 16);
        psum[m] += __shfl_xor(psum[m], 32);
    }
    if (quad == 0)
        #pragma unroll
        for (int m = 0; m < 4; ++m) ssum[w][16 * m + l15] = psum[m];
    #pragma unroll
    for (int m = 0; m < 4; ++m) {
        #pragma unroll
        for (int rr = 0; rr < 4; ++rr) {
            int il = 16 * m + quad * 4 + rr;
            float inv = 1.f / ssum[w][il];
            size_t base = ((size_t)b * 640 + i0 + il) * 256 + h * 32;
            ctx[base + l15]      = (__bf16)(o[m][0][rr] * inv);
            ctx[base + 16 + l15] = (__bf16)(o[m][1][rr] * inv);
        }
    }
}

// -------- output projection, 2-phase gll16 pipeline + VECTORIZED stores ---------------
__global__ __launch_bounds__(256, 2) void k_outproj(
    const __bf16* __restrict__ ctx,   // (b,640,256)
    const __bf16* __restrict__ WoT,   // (256,256)
    const void* __restrict__ xorig,   // dtype sniff only
    void* __restrict__ out)           // (b,256,625)
{
    __shared__ __align__(16) __bf16 pool2[20480];
    int isbf = sniff_isbf(xorig);
    int b = blockIdx.y, pt = blockIdx.x;
    int p0 = pt * 64;
    int tid = threadIdx.x, w = tid >> 6, lane = tid & 63;
    int quad = lane >> 4, l15 = lane & 15;
    int srow = tid >> 2, scg = (tid & 3) * 8;
    const __bf16* ag = ctx + ((size_t)(b * 640 + p0 + srow) * 256) + scg;
    const __bf16* bg = WoT + (size_t)srow * 256 + scg;

    gll16(ag,            &pool2[(size_t)srow * 32 + scg]);
    gll16(bg,            &pool2[2048 + (size_t)srow * 32 + scg]);
    gll16(bg + 64 * 256, &pool2[2048 + (size_t)(64 + srow) * 32 + scg]);
    gll16(bg + 128 * 256,&pool2[2048 + (size_t)(128 + srow) * 32 + scg]);
    gll16(bg + 192 * 256,&pool2[2048 + (size_t)(192 + srow) * 32 + scg]);
    __syncthreads();

    f32x4 acc[4][4] = {};
    for (int kk = 0; kk < 8; ++kk) {
        int cur = kk & 1;
        size_t base = (size_t)cur * 10240;
        if (kk < 7) {
            int c0 = (kk + 1) * 32;
            size_t nb = (size_t)(cur ^ 1) * 10240;
            gll16(ag + c0,             &pool2[nb + (size_t)srow * 32 + scg]);
            gll16(bg + c0,             &pool2[nb + 2048 + (size_t)srow * 32 + scg]);
            gll16(bg + 64 * 256 + c0,  &pool2[nb + 2048 + (size_t)(64 + srow) * 32 + scg]);
            gll16(bg + 128 * 256 + c0, &pool2[nb + 2048 + (size_t)(128 + srow) * 32 + scg]);
            gll16(bg + 192 * 256 + c0, &pool2[nb + 2048 + (size_t)(192 + srow) * 32 + scg]);
        }
        bf16x8 af[4], bfr[4];
        #pragma unroll
        for (int t = 0; t < 4; ++t) {
            af[t]  = *(const bf16x8*)(&pool2[base + (size_t)(t * 16 + l15) * 32 + quad * 8]);
            bfr[t] = *(const bf16x8*)(&pool2[base + 2048 + (size_t)(w * 64 + t * 16 + l15) * 32 + quad * 8]);
        }
        #pragma unroll
        for (int i = 0; i < 4; ++i)
            #pragma unroll
            for (int j = 0; j < 4; ++j)
                acc[i][j] = __builtin_amdgcn_mfma_f32_16x16x32_bf16(af[i], bfr[j], acc[i][j], 0, 0, 0);
        __syncthreads();
    }
    __bf16* outb = (__bf16*)out;
    float*  outf = (float*)out;
    #pragma unroll
    for (int i = 0; i < 4; ++i) {
        int p = p0 + i * 16 + quad * 4;     // multiple of 4
        #pragma unroll
        for (int j = 0; j < 4; ++j) {
            int co = w * 64 + j * 16 + l15;
            size_t o = ((size_t)(b * 256) + co) * 625 + p;
            if (p + 3 < 625) {
                if (isbf) {
                    bf16x4 v4;
                    #pragma unroll
                    for (int rr = 0; rr < 4; ++rr) v4[rr] = (__bf16)acc[i][j][rr];
                    *(bf16x4u*)(outb + o) = v4;
                } else {
                    *(f32x4u*)(outf + o) = acc[i][j];
                }
            } else {
                #pragma unroll
                for (int rr = 0; rr < 4; ++rr) {
                    if (p + rr < 625) {
                        if (isbf) outb[o + rr] = (__bf16)acc[i][j][rr];
                        else      outf[o + rr] = acc[i][j][rr];
                    }
                }
            }
        }
    }
}

extern "C" void kernel_launch(void* const* d_in, const int* in_sizes, int n_in,
                              void* d_out, int out_size, void* d_ws, size_t ws_size,
                              hipStream_t stream)
{
    const void* x    = d_in[0];
    const void* Wqkv = d_in[1];
    const void* Wout = d_in[2];
    const void* rel  = d_in[3];

    // ws layout, NO aliasing (ws_size is 256 MiB per the harness fill; we use ~70 MB).
    __bf16* ws    = (__bf16*)d_ws;
    __bf16* xT    = ws;                      // 10,485,760 elems
    __bf16* Wt    = xT + 10485760;           //    196,608
    __bf16* WoT   = Wt + 196608;             //     65,536
    __bf16* Q     = WoT + 65536;             //  5,242,880
    __bf16* Km    = Q + 5242880;             //  5,242,880
    __bf16* Vt    = Km + 5242880;            //  5,242,880
    __bf16* biasC = Vt + 5242880;            //  3,276,800
    __bf16* ctx   = biasC + 3276800;         //  5,242,880   (total ~70 MB)

    k_pre<<<1664, 256, 0, stream>>>(x, Wqkv, Wout, rel, xT, Wt, WoT, biasC);
    k_qkv<<<dim3(960), 256, 0, stream>>>(xT, Wt, Q, Km, Vt);
    k_attn<<<dim3(256, 5), 128, 0, stream>>>(Q, Km, Vt, biasC, ctx);
    k_outproj<<<dim3(10, 32), 256, 0, stream>>>(ctx, WoT, x, d_out);
}

// Round 9
// 145.916 us; speedup vs baseline: 1.3424x; 1.0108x over previous
//
#include <hip/hip_runtime.h>
#include <hip/hip_bf16.h>
#include <cstdint>

typedef __bf16 bf16x8 __attribute__((ext_vector_type(8)));
typedef __bf16 bf16x4 __attribute__((ext_vector_type(4)));
typedef float  f32x4  __attribute__((ext_vector_type(4)));
typedef float  f32x4u __attribute__((ext_vector_type(4), aligned(4)));   // 4B-aligned vec load/store
typedef __bf16 bf16x4u __attribute__((ext_vector_type(4), aligned(2)));
typedef unsigned short u16x4 __attribute__((ext_vector_type(4), aligned(2)));

__device__ __forceinline__ int div25(int v) { return (v * 1311) >> 15; }  // exact for v <= 1310

#if __has_builtin(__builtin_amdgcn_exp2f)
__device__ __forceinline__ float fast_exp2(float x) { return __builtin_amdgcn_exp2f(x); }
#else
__device__ __forceinline__ float fast_exp2(float x) { return exp2f(x); }
#endif

// async global->LDS, 16B per lane; dest must be wave-uniform base + lane*16 (linear)
__device__ __forceinline__ void gll16(const __bf16* g, __bf16* l)
{
    __builtin_amdgcn_global_load_lds(
        (__attribute__((address_space(1))) void*)(g),
        (__attribute__((address_space(3))) void*)(l),
        16, 0, 0);
}

// ---- inline dtype sniff: 16 uniform halfwords from one cache line ----
__device__ __forceinline__ int sniff_isbf(const void* p)
{
    const unsigned short* x = (const unsigned short*)p;
    int cnt = 0;
    #pragma unroll
    for (int i = 0; i < 16; ++i) {
        int e = (x[2 * i] >> 7) & 0xFF;
        cnt += (e >= 90 && e <= 143) ? 1 : 0;
    }
    return cnt > 8;
}

// ================= fused preprocessing: one launch, 3 independent jobs =================
// blocks [0,1280): x transpose+cvt, VECTORIZED (f32x4 loads, bf16x4 stores)
// blocks [1280,1344): weight prep (own 65-stride view of the shared pool)
// blocks [1344,1664): bias table, packed bf16
__global__ __launch_bounds__(256) void k_pre(
    const void* __restrict__ x, const void* __restrict__ Wqkv,
    const void* __restrict__ Wout, const void* __restrict__ rel,
    __bf16* __restrict__ xT, __bf16* __restrict__ Wt, __bf16* __restrict__ WoT,
    __bf16* __restrict__ biasC)
{
    __shared__ __align__(16) float shpool[64 * 68];   // 17.4 KB, shared by both tile users
    int bid = blockIdx.x;
    if (bid < 1280) {
        // ---- x transpose, vectorized ----
        float (*tile)[68] = (float(*)[68])shpool;     // stride 68: 16B-aligned rows
        int isbf = sniff_isbf(x);
        int b = bid / 40, rem = bid % 40;
        int c0 = (rem % 10) * 64, r0 = (rem / 10) * 64;
        const int R = 256, C = 625;
        int t = threadIdx.x;
        int lr4 = (t >> 4) * 4;    // 0..60
        int lc4 = (t & 15) * 4;    // 0..60
        const unsigned short* sb = (const unsigned short*)x + (size_t)b * (256 * 625);
        const float*          sf = (const float*)x          + (size_t)b * (256 * 625);
        #pragma unroll
        for (int rr = 0; rr < 4; ++rr) {
            int r = r0 + lr4 + rr;
            int c = c0 + lc4;
            f32x4 v = {0.f, 0.f, 0.f, 0.f};
            if (c + 3 < C) {
                if (isbf) {
                    u16x4 u = *(const u16x4*)(sb + (size_t)r * C + c);
                    #pragma unroll
                    for (int j = 0; j < 4; ++j) v[j] = __uint_as_float((unsigned)u[j] << 16);
                } else {
                    v = *(const f32x4u*)(sf + (size_t)r * C + c);
                }
            } else {
                #pragma unroll
                for (int j = 0; j < 4; ++j) {
                    int cc2 = c + j;
                    if (cc2 < C) {
                        if (isbf) v[j] = __uint_as_float((unsigned)sb[(size_t)r * C + cc2] << 16);
                        else      v[j] = sf[(size_t)r * C + cc2];
                    }
                }
            }
            *(f32x4*)(&tile[lr4 + rr][lc4]) = v;
        }
        __syncthreads();
        __bf16* d = xT + (size_t)b * (640 * 256);
        int lc = t & 63, rc = (t >> 6) * 16;
        int c = c0 + lc;
        #pragma unroll
        for (int k = 0; k < 4; ++k) {
            bf16x4 o4;
            #pragma unroll
            for (int j = 0; j < 4; ++j) o4[j] = (__bf16)tile[rc + k * 4 + j][lc];
            *(bf16x4*)(d + (size_t)c * R + r0 + rc + k * 4) = o4;
        }
    } else if (bid < 1344) {
        // ---- weight prep ----
        float (*tile)[65] = (float(*)[65])shpool;
        int q = bid - 1280;
        int bx = q % 16, by = q / 16;
        int isbf = sniff_isbf(Wqkv);
        int isqkv = (bx < 12);
        int bxx = isqkv ? bx : (bx - 12);
        const void* src = isqkv ? Wqkv : Wout;
        __bf16* dst = isqkv ? Wt : WoT;
        int R = 256, C = isqkv ? 768 : 256;
        int r0 = by * 64, c0 = bxx * 64;
        int tc = threadIdx.x & 63, tg = threadIdx.x >> 6;
        const unsigned short* sb = (const unsigned short*)src;
        const float*          sf = (const float*)src;
        #pragma unroll
        for (int rr = 0; rr < 16; ++rr) {
            int r = r0 + tg * 16 + rr, c = c0 + tc;
            float v;
            if (isbf) v = __uint_as_float((unsigned int)sb[r * C + c] << 16);
            else      v = sf[r * C + c];
            tile[tg * 16 + rr][tc] = v;
        }
        __syncthreads();
        const float qs = 0.25503494f;  // 32^-0.5 * log2(e)
        #pragma unroll
        for (int rr = 0; rr < 16; ++rr) {
            int c = c0 + tg * 16 + rr, r = r0 + tc;
            float v = tile[tc][tg * 16 + rr];
            if (isqkv && c < 256) v *= qs;
            dst[(size_t)c * R + r] = (__bf16)v;
        }
    } else {
        // ---- bias table (packed per-lane layout, bf16) ----
        const float LOG2E = 1.4426950408889634f;
        int isbf = sniff_isbf(rel);
        int q = bid - 1344;
        int ig = q % 40, h = q / 40;
        for (int t0 = 0; t0 < 10; ++t0) {
            int t  = t0 * 256 + threadIdx.x;
            int jc = t >> 7;
            int js = (t >> 6) & 1;
            int ln = t & 63;
            int qd = ln >> 4, l = ln & 15;
            int i = ig * 16 + l;
            int di = div25(i), ri = i - 25 * di;
            bf16x4 out;
            #pragma unroll
            for (int rr = 0; rr < 4; ++rr) {
                int j = jc * 32 + js * 16 + qd * 4 + rr;
                float v;
                if (j >= 625) {
                    v = -43281.f;
                } else {
                    int dj = div25(j);
                    int idx = (di - dj + 24) * 49 + ri - (j - 25 * dj) + 24;
                    idx = min(max(idx, 0), 2400);
                    float r;
                    if (isbf) r = (float)((const __bf16*)rel)[idx * 8 + h];
                    else      r = ((const float*)rel)[idx * 8 + h];
                    v = r * LOG2E;
                }
                out[rr] = (__bf16)v;
            }
            *(bf16x4*)(biasC + ((size_t)(h * 40 + ig) * 20 + jc) * 512 + ln * 8 + js * 4) = out;
        }
    }
}

// -------- QKV projection, 128x128 tile, BK=32, 2-phase double-buffered gll16 ----------
// (byte-identical to R7/R8)
#define AS(bf, r, c) pool[(size_t)(bf) * 8192 + (size_t)(r) * 32 + (c)]
#define BS(bf, r, c) pool[(size_t)(bf) * 8192 + 4096 + (size_t)(r) * 32 + (c)]
#define CS(r, c)     pool[(size_t)(r) * 44 + (c)]
__global__ __launch_bounds__(256, 2) void k_qkv(
    const __bf16* __restrict__ xT,   // (b,640,256), pad rows zeroed
    const __bf16* __restrict__ Wt,   // (768,256)
    __bf16* __restrict__ Q,          // (b,8,640,32) scaled by 32^-.5*log2e
    __bf16* __restrict__ Km,         // (b,8,640,32)
    __bf16* __restrict__ Vt)         // (b,8,32,640)
{
    __shared__ __align__(16) __bf16 pool[16384];
    int L = blockIdx.x;
    int xcd = L & 7;
    int cc  = L >> 3;
    int pairIdx = xcd * 20 + cc / 6;
    int jt = cc - (cc / 6) * 6;
    int b  = pairIdx / 5;
    int pt = pairIdx - b * 5;
    int p0 = pt * 128, j0 = jt * 128;
    int tid = threadIdx.x;
    int w = tid >> 6, lane = tid & 63;
    int quad = lane >> 4, l15 = lane & 15;
    int wr = w >> 1, wc = w & 1;

    int srow = tid >> 2, scg = (tid & 3) * 8;
    const __bf16* ag  = xT + ((size_t)(b * 640 + p0 + srow) * 256) + scg;
    const __bf16* ag2 = ag + 64 * 256;
    const __bf16* bg  = Wt + ((size_t)(j0 + srow) * 256) + scg;
    const __bf16* bg2 = bg + 64 * 256;

    gll16(ag,  &AS(0, srow, scg));
    gll16(ag2, &AS(0, 64 + srow, scg));
    gll16(bg,  &BS(0, srow, scg));
    gll16(bg2, &BS(0, 64 + srow, scg));
    __syncthreads();

    f32x4 acc[4][4] = {};
    for (int kk = 0; kk < 8; ++kk) {
        int cur = kk & 1;
        if (kk < 7) {
            int c0 = (kk + 1) * 32;
            int nb = cur ^ 1;
            gll16(ag  + c0, &AS(nb, srow, scg));
            gll16(ag2 + c0, &AS(nb, 64 + srow, scg));
            gll16(bg  + c0, &BS(nb, srow, scg));
            gll16(bg2 + c0, &BS(nb, 64 + srow, scg));
        }
        bf16x8 af[4], bfr[4];
        #pragma unroll
        for (int t = 0; t < 4; ++t) {
            af[t]  = *(const bf16x8*)(&AS(cur, wr * 64 + t * 16 + l15, quad * 8));
            bfr[t] = *(const bf16x8*)(&BS(cur, wc * 64 + t * 16 + l15, quad * 8));
        }
        #pragma unroll
        for (int i = 0; i < 4; ++i)
            #pragma unroll
            for (int j = 0; j < 4; ++j)
                acc[i][j] = __builtin_amdgcn_mfma_f32_16x16x32_bf16(af[i], bfr[j], acc[i][j], 0, 0, 0);
        __syncthreads();
    }

    if (jt < 4) {
        for (int r = 0; r < 4; ++r) {
            __syncthreads();
            if (wc == (r >> 1)) {
                #pragma unroll
                for (int i = 0; i < 4; ++i) {
                    #pragma unroll
                    for (int js = 0; js < 2; ++js) {
                        int jp = (r & 1) * 2 + js;
                        int col = js * 16 + l15;
                        int prow = wr * 64 + i * 16 + quad * 4;
                        #pragma unroll
                        for (int rr = 0; rr < 4; ++rr)
                            CS(prow + rr, col) = (__bf16)acc[i][jp][rr];
                    }
                }
            }
            __syncthreads();
            int jj = j0 + r * 32;
            __bf16* dst; int hh;
            if (jj < 256) { hh = jj >> 5; dst = Q; }
            else          { hh = (jj - 256) >> 5; dst = Km; }
            int p = tid >> 1, d0 = (tid & 1) * 16;
            size_t base = ((size_t)((b * 8 + hh) * 640) + p0 + p) * 32 + d0;
            #pragma unroll
            for (int k4 = 0; k4 < 4; ++k4) {
                bf16x4 v4 = *(const bf16x4*)(&CS(p, d0 + k4 * 4));
                *(bf16x4*)(dst + base + k4 * 4) = v4;
            }
        }
    } else {
        #pragma unroll
        for (int i = 0; i < 4; ++i) {
            #pragma unroll
            for (int j = 0; j < 4; ++j) {
                int jj = j0 + wc * 64 + j * 16 + l15 - 512;
                int h = jj >> 5, t = jj & 31;
                int p = p0 + wr * 64 + i * 16 + quad * 4;
                bf16x4 vv;
                #pragma unroll
                for (int rr = 0; rr < 4; ++rr) vv[rr] = (__bf16)acc[i][j][rr];
                *(bf16x4*)(Vt + ((size_t)((b * 8 + h) * 32) + t) * 640 + p) = vv;
            }
        }
    }
}

// -------- fused attention v14: one 640-thread block per bh (10 waves, grid 256) -------
// Same per-wave code as v11 (verified best). Wave packing only: all 10 i-tiles of one
// bh share a CU -> 10 waves/CU (31% occ, was 21%) AND single-bh K/V working set per CU
// (L1 reuse across waves; per-XCD set unchanged at 32 bh = 2.5MB < 4MB L2).
// Zero barriers; P per-wave private. Plain ctx stores (NT was the R5 poison).
__global__ __launch_bounds__(640, 2) void k_attn(
    const __bf16* __restrict__ Q,
    const __bf16* __restrict__ Km,
    const __bf16* __restrict__ Vt,
    const __bf16* __restrict__ biasC,  // packed C-fragment order, *log2e
    __bf16* __restrict__ ctx)          // (b,640,256), channel = h*32+dh
{
    __shared__ __align__(16) __bf16 P[10][2][64][44];  // [wave][buf][i][j] 112.5 KB
    __shared__ float ssum[10][64];
    int bh = blockIdx.x, b = bh >> 3, h = bh & 7;
    int tid = threadIdx.x, w = tid >> 6, lane = tid & 63;
    int quad = lane >> 4, l15 = lane & 15;
    int i0 = w * 64;

    bf16x8 qa[4];
    #pragma unroll
    for (int m = 0; m < 4; ++m)
        qa[m] = *(const bf16x8*)(Q + ((size_t)bh * 640 + i0 + 16 * m + l15) * 32 + quad * 8);
    const __bf16* kbase = Km + (size_t)bh * 640 * 32 + quad * 8;
    const __bf16* vbase = Vt + ((size_t)bh * 32 + l15) * 640 + quad * 8;
    const __bf16* bcb   = biasC + (size_t)(h * 40 + (i0 >> 4)) * 10240 + lane * 8;

    f32x4 o[4][2] = {};
    float psum[4] = {0.f, 0.f, 0.f, 0.f};

    bf16x8 k0 = *(const bf16x8*)(kbase + (size_t)l15 * 32);
    bf16x8 k1 = *(const bf16x8*)(kbase + (size_t)(16 + l15) * 32);
    bf16x8 bc[4];
    #pragma unroll
    for (int m = 0; m < 4; ++m)
        bc[m] = *(const bf16x8*)(bcb + m * 10240);
    bf16x8 vC0 = {}, vC1 = {};

    for (int c = 0; c < 20; ++c) {
        int buf = c & 1;
        f32x4 s[4][2];
        __builtin_amdgcn_s_setprio(1);
        #pragma unroll
        for (int m = 0; m < 4; ++m) {
            f32x4 f0, f1;
            #pragma unroll
            for (int rr = 0; rr < 4; ++rr) { f0[rr] = (float)bc[m][rr]; f1[rr] = (float)bc[m][4 + rr]; }
            s[m][0] = __builtin_amdgcn_mfma_f32_16x16x32_bf16(k0, qa[m], f0, 0, 0, 0);
            s[m][1] = __builtin_amdgcn_mfma_f32_16x16x32_bf16(k1, qa[m], f1, 0, 0, 0);
        }
        __builtin_amdgcn_s_setprio(0);
        int cn = min(c + 1, 19);
        bf16x8 k0n = *(const bf16x8*)(kbase + (size_t)(cn * 32 + l15) * 32);
        bf16x8 k1n = *(const bf16x8*)(kbase + (size_t)(cn * 32 + 16 + l15) * 32);
        bf16x8 vN0 = *(const bf16x8*)(vbase + c * 32);
        bf16x8 vN1 = *(const bf16x8*)(vbase + (size_t)16 * 640 + c * 32);
        bf16x8 bn[4];
        #pragma unroll
        for (int m = 0; m < 4; ++m)
            bn[m] = *(const bf16x8*)(bcb + m * 10240 + cn * 512);
        bf16x4 pk[4][2];
        #pragma unroll
        for (int m = 0; m < 4; ++m) {
            #pragma unroll
            for (int rr = 0; rr < 4; ++rr) {
                float e0 = fast_exp2(s[m][0][rr]); psum[m] += e0; pk[m][0][rr] = (__bf16)e0;
                float e1 = fast_exp2(s[m][1][rr]); psum[m] += e1; pk[m][1][rr] = (__bf16)e1;
            }
        }
        if (c > 0) {
            __builtin_amdgcn_s_setprio(1);
            #pragma unroll
            for (int m = 0; m < 4; ++m) {
                bf16x8 pa = *(const bf16x8*)(&P[w][buf ^ 1][16 * m + l15][quad * 8]);
                o[m][0] = __builtin_amdgcn_mfma_f32_16x16x32_bf16(pa, vC0, o[m][0], 0, 0, 0);
                o[m][1] = __builtin_amdgcn_mfma_f32_16x16x32_bf16(pa, vC1, o[m][1], 0, 0, 0);
            }
            __builtin_amdgcn_s_setprio(0);
        }
        #pragma unroll
        for (int m = 0; m < 4; ++m) {
            *(bf16x4*)(&P[w][buf][16 * m + l15][quad * 4])      = pk[m][0];
            *(bf16x4*)(&P[w][buf][16 * m + l15][16 + quad * 4]) = pk[m][1];
        }
        k0 = k0n; k1 = k1n; vC0 = vN0; vC1 = vN1;
        #pragma unroll
        for (int m = 0; m < 4; ++m) bc[m] = bn[m];
    }
    __builtin_amdgcn_s_setprio(1);
    #pragma unroll
    for (int m = 0; m < 4; ++m) {
        bf16x8 pa = *(const bf16x8*)(&P[w][1][16 * m + l15][quad * 8]);
        o[m][0] = __builtin_amdgcn_mfma_f32_16x16x32_bf16(pa, vC0, o[m][0], 0, 0, 0);
        o[m][1] = __builtin_amdgcn_mfma_f32_16x16x32_bf16(pa, vC1, o[m][1], 0, 0, 0);
    }
    __builtin_amdgcn_s_setprio(0);

    #pragma unroll
    for (int m = 0; m < 4; ++m) {
        psum[m] += __shfl_xor(psum[m], 16);
        psum[m] += __shfl_xor(psum[m], 32);
    }
    if (quad == 0)
        #pragma unroll
        for (int m = 0; m < 4; ++m) ssum[w][16 * m + l15] = psum[m];
    #pragma unroll
    for (int m = 0; m < 4; ++m) {
        #pragma unroll
        for (int rr = 0; rr < 4; ++rr) {
            int il = 16 * m + quad * 4 + rr;
            float inv = 1.f / ssum[w][il];
            size_t base = ((size_t)b * 640 + i0 + il) * 256 + h * 32;
            ctx[base + l15]      = (__bf16)(o[m][0][rr] * inv);
            ctx[base + 16 + l15] = (__bf16)(o[m][1][rr] * inv);
        }
    }
}

// -------- output projection, 2-phase gll16 pipeline + VECTORIZED stores ---------------
// (byte-identical to R8)
__global__ __launch_bounds__(256, 2) void k_outproj(
    const __bf16* __restrict__ ctx,   // (b,640,256)
    const __bf16* __restrict__ WoT,   // (256,256)
    const void* __restrict__ xorig,   // dtype sniff only
    void* __restrict__ out)           // (b,256,625)
{
    __shared__ __align__(16) __bf16 pool2[20480];
    int isbf = sniff_isbf(xorig);
    int b = blockIdx.y, pt = blockIdx.x;
    int p0 = pt * 64;
    int tid = threadIdx.x, w = tid >> 6, lane = tid & 63;
    int quad = lane >> 4, l15 = lane & 15;
    int srow = tid >> 2, scg = (tid & 3) * 8;
    const __bf16* ag = ctx + ((size_t)(b * 640 + p0 + srow) * 256) + scg;
    const __bf16* bg = WoT + (size_t)srow * 256 + scg;

    gll16(ag,            &pool2[(size_t)srow * 32 + scg]);
    gll16(bg,            &pool2[2048 + (size_t)srow * 32 + scg]);
    gll16(bg + 64 * 256, &pool2[2048 + (size_t)(64 + srow) * 32 + scg]);
    gll16(bg + 128 * 256,&pool2[2048 + (size_t)(128 + srow) * 32 + scg]);
    gll16(bg + 192 * 256,&pool2[2048 + (size_t)(192 + srow) * 32 + scg]);
    __syncthreads();

    f32x4 acc[4][4] = {};
    for (int kk = 0; kk < 8; ++kk) {
        int cur = kk & 1;
        size_t base = (size_t)cur * 10240;
        if (kk < 7) {
            int c0 = (kk + 1) * 32;
            size_t nb = (size_t)(cur ^ 1) * 10240;
            gll16(ag + c0,             &pool2[nb + (size_t)srow * 32 + scg]);
            gll16(bg + c0,             &pool2[nb + 2048 + (size_t)srow * 32 + scg]);
            gll16(bg + 64 * 256 + c0,  &pool2[nb + 2048 + (size_t)(64 + srow) * 32 + scg]);
            gll16(bg + 128 * 256 + c0, &pool2[nb + 2048 + (size_t)(128 + srow) * 32 + scg]);
            gll16(bg + 192 * 256 + c0, &pool2[nb + 2048 + (size_t)(192 + srow) * 32 + scg]);
        }
        bf16x8 af[4], bfr[4];
        #pragma unroll
        for (int t = 0; t < 4; ++t) {
            af[t]  = *(const bf16x8*)(&pool2[base + (size_t)(t * 16 + l15) * 32 + quad * 8]);
            bfr[t] = *(const bf16x8*)(&pool2[base + 2048 + (size_t)(w * 64 + t * 16 + l15) * 32 + quad * 8]);
        }
        #pragma unroll
        for (int i = 0; i < 4; ++i)
            #pragma unroll
            for (int j = 0; j < 4; ++j)
                acc[i][j] = __builtin_amdgcn_mfma_f32_16x16x32_bf16(af[i], bfr[j], acc[i][j], 0, 0, 0);
        __syncthreads();
    }
    __bf16* outb = (__bf16*)out;
    float*  outf = (float*)out;
    #pragma unroll
    for (int i = 0; i < 4; ++i) {
        int p = p0 + i * 16 + quad * 4;
        #pragma unroll
        for (int j = 0; j < 4; ++j) {
            int co = w * 64 + j * 16 + l15;
            size_t o = ((size_t)(b * 256) + co) * 625 + p;
            if (p + 3 < 625) {
                if (isbf) {
                    bf16x4 v4;
                    #pragma unroll
                    for (int rr = 0; rr < 4; ++rr) v4[rr] = (__bf16)acc[i][j][rr];
                    *(bf16x4u*)(outb + o) = v4;
                } else {
                    *(f32x4u*)(outf + o) = acc[i][j];
                }
            } else {
                #pragma unroll
                for (int rr = 0; rr < 4; ++rr) {
                    if (p + rr < 625) {
                        if (isbf) outb[o + rr] = (__bf16)acc[i][j][rr];
                        else      outf[o + rr] = acc[i][j][rr];
                    }
                }
            }
        }
    }
}

extern "C" void kernel_launch(void* const* d_in, const int* in_sizes, int n_in,
                              void* d_out, int out_size, void* d_ws, size_t ws_size,
                              hipStream_t stream)
{
    const void* x    = d_in[0];
    const void* Wqkv = d_in[1];
    const void* Wout = d_in[2];
    const void* rel  = d_in[3];

    // ws layout, NO aliasing (ws_size is 256 MiB per the harness fill; we use ~70 MB).
    __bf16* ws    = (__bf16*)d_ws;
    __bf16* xT    = ws;                      // 10,485,760 elems
    __bf16* Wt    = xT + 10485760;           //    196,608
    __bf16* WoT   = Wt + 196608;             //     65,536
    __bf16* Q     = WoT + 65536;             //  5,242,880
    __bf16* Km    = Q + 5242880;             //  5,242,880
    __bf16* Vt    = Km + 5242880;            //  5,242,880
    __bf16* biasC = Vt + 5242880;            //  3,276,800
    __bf16* ctx   = biasC + 3276800;         //  5,242,880   (total ~70 MB)

    k_pre<<<1664, 256, 0, stream>>>(x, Wqkv, Wout, rel, xT, Wt, WoT, biasC);
    k_qkv<<<dim3(960), 256, 0, stream>>>(xT, Wt, Q, Km, Vt);
    k_attn<<<dim3(256), 640, 0, stream>>>(Q, Km, Vt, biasC, ctx);
    k_outproj<<<dim3(10, 32), 256, 0, stream>>>(ctx, WoT, x, d_out);
}